// Round 14
// baseline (249.804 us; speedup 1.0000x reference)
//
#include <hip/hip_runtime.h>

constexpr int B_ = 2, N_ = 2048, C_ = 1024, H_ = 16, HD_ = 64, FF_ = 2048;

typedef __attribute__((ext_vector_type(8))) __bf16 bf16x8;
typedef __attribute__((ext_vector_type(2))) __bf16 bf16x2;
typedef __attribute__((ext_vector_type(4))) float f32x4;
typedef __attribute__((ext_vector_type(16))) float f32x16;

#define WAITVM(n) asm volatile("s_waitcnt vmcnt(" #n ")" ::: "memory")
#define WAITLGKM0 asm volatile("s_waitcnt lgkmcnt(0)" ::: "memory")

__device__ __forceinline__ unsigned short f2bf(float f) {
  union { float f; unsigned int u; } v; v.f = f;
  unsigned int r = v.u + 0x7fffu + ((v.u >> 16) & 1u);
  return (unsigned short)(r >> 16);
}

__device__ __forceinline__ unsigned pk2(float a, float b) {
  bf16x2 p;
  p[0] = (__bf16)a;
  p[1] = (__bf16)b;
  union { bf16x2 v; unsigned u; } u;
  u.v = p;
  return u.u;
}

__device__ __forceinline__ float max3f(float a, float b, float c) {
  return fmaxf(fmaxf(a, b), c);  // clang fuses to v_max3_f32
}

// v_permlane32_swap_b32 D,S:  newD = {D.lo, S.lo}, newS = {D.hi, S.hi}
__device__ __forceinline__ void pl32swap(unsigned& d, unsigned& s) {
  asm volatile("v_permlane32_swap_b32 %0, %1" : "+v"(d), "+v"(s));
}

__device__ __forceinline__ void gload_lds16(const unsigned short* g, unsigned short* l) {
  __builtin_amdgcn_global_load_lds((const __attribute__((address_space(1))) void*)g,
                                   (__attribute__((address_space(3))) void*)l, 16, 0, 0);
}

// XCD-chunk swizzle (attn only)
__device__ __forceinline__ int xcd_chunk(int bid, int nwg) {
  return (bid & 7) * (nwg >> 3) + (bid >> 3);
}

// ---------------- cast f32 -> bf16, z-fused over q,k,v ----------------
__global__ __launch_bounds__(256)
void cast3_bf16(const float* __restrict__ q, const float* __restrict__ k,
                const float* __restrict__ v, unsigned short* __restrict__ qo,
                unsigned short* __restrict__ ko, unsigned short* __restrict__ vo, int n8) {
  int i = blockIdx.x * 256 + threadIdx.x;
  if (i >= n8) return;
  const float* in = blockIdx.z == 0 ? q : (blockIdx.z == 1 ? k : v);
  unsigned short* out = blockIdx.z == 0 ? qo : (blockIdx.z == 1 ? ko : vo);
  const float4 a = ((const float4*)in)[2 * i];
  const float4 b = ((const float4*)in)[2 * i + 1];
  uint4 o;
  o.x = (unsigned)f2bf(a.x) | ((unsigned)f2bf(a.y) << 16);
  o.y = (unsigned)f2bf(a.z) | ((unsigned)f2bf(a.w) << 16);
  o.z = (unsigned)f2bf(b.x) | ((unsigned)f2bf(b.y) << 16);
  o.w = (unsigned)f2bf(b.z) | ((unsigned)f2bf(b.w) << 16);
  ((uint4*)out)[i] = o;
}

// ---------------- cast+transpose weights: W[K][N] f32 -> Wt[N][K] bf16 ----------------
__global__ __launch_bounds__(256)
void wt_cast(const float* __restrict__ W, unsigned short* __restrict__ Wt, int K, int N) {
  __shared__ unsigned short tile[32][33];
  const int tx = threadIdx.x, ty = threadIdx.y;
  const int n0 = blockIdx.x * 32, k0 = blockIdx.y * 32;
#pragma unroll
  for (int r = 0; r < 4; ++r)
    tile[ty + r * 8][tx] = f2bf(W[(size_t)(k0 + ty + r * 8) * N + n0 + tx]);
  __syncthreads();
#pragma unroll
  for (int r = 0; r < 4; ++r)
    Wt[(size_t)(n0 + ty + r * 8) * K + k0 + tx] = tile[tx][ty + r * 8];
}

// z-fused version for the four C x C weights
__global__ __launch_bounds__(256)
void wt_cast4(const float* __restrict__ Wa, const float* __restrict__ Wb,
              const float* __restrict__ Wc, const float* __restrict__ Wd,
              unsigned short* __restrict__ Oa, unsigned short* __restrict__ Ob,
              unsigned short* __restrict__ Oc, unsigned short* __restrict__ Od) {
  __shared__ unsigned short tile[32][33];
  const int z = blockIdx.z;
  const float* W = z == 0 ? Wa : (z == 1 ? Wb : (z == 2 ? Wc : Wd));
  unsigned short* Wt = z == 0 ? Oa : (z == 1 ? Ob : (z == 2 ? Oc : Od));
  const int tx = threadIdx.x, ty = threadIdx.y;
  const int n0 = blockIdx.x * 32, k0 = blockIdx.y * 32;
#pragma unroll
  for (int r = 0; r < 4; ++r)
    tile[ty + r * 8][tx] = f2bf(W[(size_t)(k0 + ty + r * 8) * C_ + n0 + tx]);
  __syncthreads();
#pragma unroll
  for (int r = 0; r < 4; ++r)
    Wt[(size_t)(n0 + ty + r * 8) * C_ + k0 + tx] = tile[tx][ty + r * 8];
}

// ---------------- Vh [B,N,H,HD] -> VhT [B,H,HD,N] (bf16) ----------------
__global__ __launch_bounds__(256)
void vh_transpose(const unsigned short* __restrict__ Vh, unsigned short* __restrict__ VhT) {
  __shared__ unsigned short tile[32][33];
  const int tx = threadIdx.x, ty = threadIdx.y;
  const int bh = blockIdx.z, b = bh >> 4, h = bh & 15;
  const int n0 = blockIdx.x * 32, d0 = blockIdx.y * 32;
#pragma unroll
  for (int r = 0; r < 4; ++r) {
    int n = n0 + ty + r * 8;
    tile[ty + r * 8][tx] = Vh[((size_t)(b * N_ + n)) * C_ + h * HD_ + d0 + tx];
  }
  __syncthreads();
#pragma unroll
  for (int r = 0; r < 4; ++r) {
    int d = d0 + ty + r * 8;
    VhT[((size_t)(bh * HD_ + d)) * N_ + n0 + tx] = tile[tx][ty + r * 8];
  }
}

// ---------------- 128x128 GEMM (2-phase dbuf), z-fused QKV (out bf16) ----------------
// z==0 (Q) output pre-scaled by c1 = 1/sqrt(HD) * log2(e) for log2-domain softmax.
__global__ __launch_bounds__(256, 2)
void gemm_qkv(const unsigned short* __restrict__ A0, const unsigned short* __restrict__ A1,
              const unsigned short* __restrict__ A2, const unsigned short* __restrict__ B0,
              const unsigned short* __restrict__ B1, const unsigned short* __restrict__ B2,
              const float* __restrict__ c0, const float* __restrict__ c1v,
              const float* __restrict__ c2, unsigned short* __restrict__ O0,
              unsigned short* __restrict__ O1, unsigned short* __restrict__ O2) {
  const int z = blockIdx.z;
  const unsigned short* A = z == 0 ? A0 : (z == 1 ? A1 : A2);
  const unsigned short* Bt = z == 0 ? B0 : (z == 1 ? B1 : B2);
  const float* bias = z == 0 ? c0 : (z == 1 ? c1v : c2);
  unsigned short* outB = z == 0 ? O0 : (z == 1 ? O1 : O2);
  const float sc = z == 0 ? 0.18033688011112042f : 1.0f;
  const int K = C_, Nn = C_;

  __shared__ unsigned short lA[2][128 * 64];
  __shared__ unsigned short lB[2][128 * 64];
  const int t = threadIdx.x;
  const int lane = t & 63;
  const int w = t >> 6;
  const int wm = w >> 1, wn = w & 1;
  const int l15 = lane & 15, g = lane >> 4;

  const unsigned short* Ab = A + (size_t)blockIdx.x * 128 * K;
  const unsigned short* Bb = Bt + (size_t)blockIdx.y * 128 * K;

  auto stage = [&](int buf, int k0) {
#pragma unroll
    for (int i = 0; i < 4; ++i) {
      int id = i * 256 + t;
      gload_lds16(Ab + (size_t)(id >> 3) * K + k0 + (id & 7) * 8, &lA[buf][id * 8]);
    }
#pragma unroll
    for (int i = 0; i < 4; ++i) {
      int id = i * 256 + t;
      gload_lds16(Bb + (size_t)(id >> 3) * K + k0 + (id & 7) * 8, &lB[buf][id * 8]);
    }
  };

  f32x4 acc[4][4] = {};

  stage(0, 0);
  __syncthreads();
  int cur = 0;
  for (int k0 = 0; k0 < K; k0 += 64) {
    if (k0 + 64 < K) stage(cur ^ 1, k0 + 64);
#pragma unroll
    for (int kk = 0; kk < 2; ++kk) {
      bf16x8 af[4], bfr[4];
#pragma unroll
      for (int mi = 0; mi < 4; ++mi)
        af[mi] = *(const bf16x8*)&lA[cur][(wm * 64 + mi * 16 + l15) * 64 + kk * 32 + g * 8];
#pragma unroll
      for (int ni = 0; ni < 4; ++ni)
        bfr[ni] = *(const bf16x8*)&lB[cur][(wn * 64 + ni * 16 + l15) * 64 + kk * 32 + g * 8];
      __builtin_amdgcn_s_setprio(1);
#pragma unroll
      for (int mi = 0; mi < 4; ++mi)
#pragma unroll
        for (int ni = 0; ni < 4; ++ni)
          acc[mi][ni] = __builtin_amdgcn_mfma_f32_16x16x32_bf16(af[mi], bfr[ni], acc[mi][ni], 0, 0, 0);
      __builtin_amdgcn_s_setprio(0);
    }
    __syncthreads();
    cur ^= 1;
  }

#pragma unroll
  for (int mi = 0; mi < 4; ++mi)
#pragma unroll
    for (int ni = 0; ni < 4; ++ni) {
      const int col = blockIdx.y * 128 + wn * 64 + ni * 16 + l15;
      const float bcol = bias[col];
#pragma unroll
      for (int r = 0; r < 4; ++r) {
        const int row = blockIdx.x * 128 + wm * 64 + mi * 16 + g * 4 + r;
        outB[(size_t)row * Nn + col] = f2bf((acc[mi][ni][r] + bcol) * sc);
      }
    }
}

// ---------------- 128x64-tile GEMM (2-phase dbuf), templated epilogue ----------------
// EPI 1: outF = v + bias + resid (f32) ; EPI 2: outB = gelu(v + bias) (bf16)
template <int EPI>
__global__ __launch_bounds__(256, 2)
void gemm_n64(const unsigned short* __restrict__ A, const unsigned short* __restrict__ Bt,
              const float* __restrict__ bias, const float* __restrict__ resid,
              float* __restrict__ outF, unsigned short* __restrict__ outB,
              int M, int N, int K) {
  __shared__ unsigned short lA[2][128 * 64];
  __shared__ unsigned short lB[2][64 * 64];
  const int t = threadIdx.x;
  const int lane = t & 63;
  const int w = t >> 6;
  const int wm = w >> 1, wn = w & 1;
  const int l15 = lane & 15, g = lane >> 4;

  const unsigned short* Ab = A + (size_t)blockIdx.x * 128 * K;
  const unsigned short* Bb = Bt + (size_t)blockIdx.y * 64 * K;

  auto stage = [&](int buf, int k0) {
#pragma unroll
    for (int i = 0; i < 4; ++i) {
      int id = i * 256 + t;
      gload_lds16(Ab + (size_t)(id >> 3) * K + k0 + (id & 7) * 8, &lA[buf][id * 8]);
    }
#pragma unroll
    for (int i = 0; i < 2; ++i) {
      int id = i * 256 + t;
      gload_lds16(Bb + (size_t)(id >> 3) * K + k0 + (id & 7) * 8, &lB[buf][id * 8]);
    }
  };

  f32x4 acc[4][2] = {};

  stage(0, 0);
  __syncthreads();
  int cur = 0;
  for (int k0 = 0; k0 < K; k0 += 64) {
    if (k0 + 64 < K) stage(cur ^ 1, k0 + 64);
#pragma unroll
    for (int kk = 0; kk < 2; ++kk) {
      bf16x8 af[4], bfr[2];
#pragma unroll
      for (int mi = 0; mi < 4; ++mi)
        af[mi] = *(const bf16x8*)&lA[cur][(wm * 64 + mi * 16 + l15) * 64 + kk * 32 + g * 8];
#pragma unroll
      for (int ni = 0; ni < 2; ++ni)
        bfr[ni] = *(const bf16x8*)&lB[cur][(wn * 32 + ni * 16 + l15) * 64 + kk * 32 + g * 8];
      __builtin_amdgcn_s_setprio(1);
#pragma unroll
      for (int mi = 0; mi < 4; ++mi)
#pragma unroll
        for (int ni = 0; ni < 2; ++ni)
          acc[mi][ni] = __builtin_amdgcn_mfma_f32_16x16x32_bf16(af[mi], bfr[ni], acc[mi][ni], 0, 0, 0);
      __builtin_amdgcn_s_setprio(0);
    }
    __syncthreads();
    cur ^= 1;
  }

#pragma unroll
  for (int mi = 0; mi < 4; ++mi)
#pragma unroll
    for (int ni = 0; ni < 2; ++ni) {
      const int col = blockIdx.y * 64 + wn * 32 + ni * 16 + l15;
      const float bcol = bias[col];
#pragma unroll
      for (int r = 0; r < 4; ++r) {
        const int row = blockIdx.x * 128 + wm * 64 + mi * 16 + g * 4 + r;
        const size_t o = (size_t)row * N + col;
        float val = acc[mi][ni][r] + bcol;
        if (EPI == 1) {
          outF[o] = val + resid[o];
        } else {
          float ge = 0.5f * val * (1.0f + erff(val * 0.70710678118654752f));
          outB[o] = f2bf(ge);
        }
      }
    }
}

// ---------------- flash attention v12: + tree-max (max3) + 4-chain sum ----------------
// 512 blocks (XCD-chunk swizzled), 256 threads = 4 waves, 32 q-rows per wave.
// QK^T: S^T = mfma_32x32x16(K_frag, Q_frag); P repack via v_permlane32_swap;
// PV: mfma_32x32x16(V^T, P). K/V LDS XOR-swizzled, counted vmcnt.
// Q pre-scaled by c1 -> S in log2 units.
__global__ __launch_bounds__(256, 2)
void attn_fwd(const unsigned short* __restrict__ Qh, const unsigned short* __restrict__ Kh,
              const unsigned short* __restrict__ VhT, unsigned short* __restrict__ ctx) {
  __shared__ unsigned short lK[2][64 * 64];
  __shared__ unsigned short lV[2][64 * 64];

  const int t = threadIdx.x, lane = t & 63, w = t >> 6;
  const int l31 = lane & 31, hl = lane >> 5;
  const int swz = xcd_chunk(blockIdx.x, (N_ / 128) * B_ * H_);
  const int bx = swz & (N_ / 128 - 1), bh = swz >> 4;
  const int b = bh >> 4, h = bh & 15;
  const int qb0 = bx * 128 + w * 32;

  const unsigned short* Qb = Qh + (size_t)b * N_ * C_ + h * HD_;
  const unsigned short* Kb = Kh + (size_t)b * N_ * C_ + h * HD_;
  const unsigned short* Vb = VhT + (size_t)bh * HD_ * N_;

  // Q frags (B-operand): lane holds Q[q = qb0+l31][d = f*16 + hl*8 + j]
  bf16x8 qf[4];
#pragma unroll
  for (int f = 0; f < 4; ++f)
    qf[f] = *(const bf16x8*)(Qb + (size_t)(qb0 + l31) * C_ + f * 16 + hl * 8);

  // stage: linear LDS dest, inverse-swizzled global source (rule #21)
  auto stageK = [&](int buf, int kb) {
#pragma unroll
    for (int i = 0; i < 2; ++i) {
      int o = (i * 256 + t) * 16;                 // tile byte offset
      int r = o >> 7;                             // row (key)
      int c = (o & 127) ^ ((r & 7) << 4);         // swizzled byte col
      gload_lds16(Kb + (size_t)(kb + r) * C_ + (c >> 1), &lK[buf][o >> 1]);
    }
  };
  auto stageV = [&](int buf, int kb) {
#pragma unroll
    for (int i = 0; i < 2; ++i) {
      int o = (i * 256 + t) * 16;
      int r = o >> 7;                             // row (d)
      int c = (o & 127) ^ ((r & 7) << 4);
      gload_lds16(Vb + (size_t)r * N_ + kb + (c >> 1), &lV[buf][o >> 1]);
    }
  };

  f32x16 od[2] = {};
  float mrun = -1e30f;
  float ps[4] = {0.f, 0.f, 0.f, 0.f};     // 4 independent partial-sum chains
  const float DTHR = 11.541560327111707f;  // 8 * log2(e)
  const int NT = N_ / 64;
  const int sw = (l31 & 7) << 4;           // byte-swizzle for LDS reads

  stageK(0, 0);
  stageV(0, 0);

  int cur = 0;
  for (int tile = 0; tile < NT; ++tile) {
    if (tile + 1 < NT) {
      stageK(cur ^ 1, (tile + 1) * 64);
      stageV(cur ^ 1, (tile + 1) * 64);
      WAITVM(4);            // current tile staged; next tile's 4 loads in flight
    } else {
      WAITVM(0);
    }
    __builtin_amdgcn_s_barrier();

    // ---- QK^T: S^T[key][q] per 32-key block ----
    f32x16 st[2];
    __builtin_amdgcn_s_setprio(1);
#pragma unroll
    for (int kb2 = 0; kb2 < 2; ++kb2) {
      f32x16 z = {};
#pragma unroll
      for (int f = 0; f < 4; ++f) {
        const int byt = (kb2 * 32 + l31) * 128 + ((f * 32 + hl * 16) ^ sw);
        const bf16x8 ka = *(const bf16x8*)&lK[cur][byt >> 1];
        z = __builtin_amdgcn_mfma_f32_32x32x16_bf16(ka, qf[f], z, 0, 0, 0);
      }
      st[kb2] = z;
    }
    __builtin_amdgcn_s_setprio(0);

    // ---- tree max-reduce (pairwise + v_max3; depth ~5 vs 31-deep chain) ----
    float mp[16];
#pragma unroll
    for (int r = 0; r < 16; ++r) mp[r] = fmaxf(st[0][r], st[1][r]);
    {
      const float t0 = max3f(mp[0], mp[1], mp[2]);
      const float t1 = max3f(mp[3], mp[4], mp[5]);
      const float t2 = max3f(mp[6], mp[7], mp[8]);
      const float t3 = max3f(mp[9], mp[10], mp[11]);
      const float t4 = max3f(mp[12], mp[13], mp[14]);
      const float u0 = max3f(t0, t1, mp[15]);
      const float u1 = max3f(t2, t3, t4);
      float mx = fmaxf(u0, u1);
      mx = fmaxf(mx, __shfl_xor(mx, 32));
      if (__any(mx > mrun + DTHR)) {
        const float mn = fmaxf(mrun, mx);
        const float sf = exp2f(mrun - mn);
        mrun = mn;
#pragma unroll
        for (int i = 0; i < 4; ++i) ps[i] *= sf;
#pragma unroll
        for (int dblk = 0; dblk < 2; ++dblk)
#pragma unroll
          for (int r = 0; r < 16; ++r) od[dblk][r] *= sf;
      }
    }

    // ---- P = exp2(S - m), 4-chain sum, repack via permlane32_swap ----
    bf16x8 pb[4];
#pragma unroll
    for (int kb2 = 0; kb2 < 2; ++kb2) {
      float p[16];
#pragma unroll
      for (int r = 0; r < 16; ++r) {
        p[r] = exp2f(st[kb2][r] - mrun);
        ps[r & 3] += p[r];
      }
      unsigned qd[8];
#pragma unroll
      for (int i = 0; i < 8; ++i) qd[i] = pk2(p[2 * i], p[2 * i + 1]);
      pl32swap(qd[0], qd[2]);
      pl32swap(qd[1], qd[3]);
      pl32swap(qd[4], qd[6]);
      pl32swap(qd[5], qd[7]);
      union { unsigned u[4]; bf16x8 v; } f0, f1;
      f0.u[0] = qd[0];
      f0.u[1] = qd[1];
      f0.u[2] = qd[2];
      f0.u[3] = qd[3];
      f1.u[0] = qd[4];
      f1.u[1] = qd[5];
      f1.u[2] = qd[6];
      f1.u[3] = qd[7];
      pb[kb2 * 2 + 0] = f0.v;
      pb[kb2 * 2 + 1] = f1.v;
    }

    // ---- PV: O^T += V^T * P ----
    __builtin_amdgcn_s_setprio(1);
#pragma unroll
    for (int dblk = 0; dblk < 2; ++dblk) {
#pragma unroll
      for (int kf = 0; kf < 4; ++kf) {
        const int byt = (dblk * 32 + l31) * 128 + ((kf * 32 + hl * 16) ^ sw);
        const bf16x8 va = *(const bf16x8*)&lV[cur][byt >> 1];
        od[dblk] = __builtin_amdgcn_mfma_f32_32x32x16_bf16(va, pb[kf], od[dblk], 0, 0, 0);
      }
    }
    __builtin_amdgcn_s_setprio(0);

    WAITLGKM0;              // own LDS reads retired before buffer overwrite
    __builtin_amdgcn_s_barrier();
    cur ^= 1;
  }

  float srun = (ps[0] + ps[1]) + (ps[2] + ps[3]);
  float s = srun + __shfl_xor(srun, 32);
  const float rinv = 1.0f / s;
  unsigned short* cp = ctx + ((size_t)(b * N_ + qb0 + l31)) * C_ + h * HD_;
#pragma unroll
  for (int dblk = 0; dblk < 2; ++dblk)
#pragma unroll
    for (int a = 0; a < 4; ++a) {
      const int r0 = a * 4;
      uint2 o;
      o.x = pk2(od[dblk][r0] * rinv, od[dblk][r0 + 1] * rinv);
      o.y = pk2(od[dblk][r0 + 2] * rinv, od[dblk][r0 + 3] * rinv);
      *(uint2*)(cp + dblk * 32 + a * 8 + hl * 4) = o;
    }
}

// ---------------- LayerNorm: x f32 [BN, C] -> h bf16 ----------------
__global__ __launch_bounds__(256)
void ln_kernel(const float* __restrict__ x, const float* __restrict__ lw,
               const float* __restrict__ lb, unsigned short* __restrict__ h) {
  const int row = blockIdx.x;
  const int t = threadIdx.x;
  const float4 v = ((const float4*)(x + (size_t)row * C_))[t];
  float sum = v.x + v.y + v.z + v.w;
#pragma unroll
  for (int m = 1; m < 64; m <<= 1) sum += __shfl_xor(sum, m);
  __shared__ float red[8];
  if ((t & 63) == 0) red[t >> 6] = sum;
  __syncthreads();
  const float mu = (red[0] + red[1] + red[2] + red[3]) * (1.0f / C_);
  const float d0 = v.x - mu, d1 = v.y - mu, d2 = v.z - mu, d3 = v.w - mu;
  float sq = d0 * d0 + d1 * d1 + d2 * d2 + d3 * d3;
#pragma unroll
  for (int m = 1; m < 64; m <<= 1) sq += __shfl_xor(sq, m);
  if ((t & 63) == 0) red[4 + (t >> 6)] = sq;
  __syncthreads();
  const float var = (red[4] + red[5] + red[6] + red[7]) * (1.0f / C_);
  const float rstd = rsqrtf(var + 1e-5f);
  const float4 ww = ((const float4*)lw)[t];
  const float4 bb = ((const float4*)lb)[t];
  uint2 o;
  o.x = (unsigned)f2bf(d0 * rstd * ww.x + bb.x) | ((unsigned)f2bf(d1 * rstd * ww.y + bb.y) << 16);
  o.y = (unsigned)f2bf(d2 * rstd * ww.z + bb.z) | ((unsigned)f2bf(d3 * rstd * ww.w + bb.w) << 16);
  ((uint2*)(h + (size_t)row * C_))[t] = o;
}

extern "C" void kernel_launch(void* const* d_in, const int* in_sizes, int n_in,
                              void* d_out, int out_size, void* d_ws, size_t ws_size,
                              hipStream_t stream) {
  const float* q   = (const float*)d_in[0];
  const float* k   = (const float*)d_in[1];
  const float* v   = (const float*)d_in[2];
  const float* Wq  = (const float*)d_in[3];
  const float* bq  = (const float*)d_in[4];
  const float* Wk  = (const float*)d_in[5];
  const float* bk  = (const float*)d_in[6];
  const float* Wv  = (const float*)d_in[7];
  const float* bv  = (const float*)d_in[8];
  const float* Wo  = (const float*)d_in[9];
  const float* bo  = (const float*)d_in[10];
  const float* lnw = (const float*)d_in[11];
  const float* lnb = (const float*)d_in[12];
  const float* W1  = (const float*)d_in[13];
  const float* b1  = (const float*)d_in[14];
  const float* W2  = (const float*)d_in[15];
  const float* b2  = (const float*)d_in[16];
  float* out = (float*)d_out;

  char* ws = (char*)d_ws;
  const size_t MB = 1024 * 1024;
  if (ws_size < 120 * MB) return;
  unsigned short* qb   = (unsigned short*)(ws + 0 * MB);
  unsigned short* kb   = (unsigned short*)(ws + 8 * MB);
  unsigned short* vb   = (unsigned short*)(ws + 16 * MB);
  unsigned short* Wqt  = (unsigned short*)(ws + 24 * MB);
  unsigned short* Wkt  = (unsigned short*)(ws + 26 * MB);
  unsigned short* Wvt  = (unsigned short*)(ws + 28 * MB);
  unsigned short* Wot  = (unsigned short*)(ws + 30 * MB);
  unsigned short* W1t  = (unsigned short*)(ws + 32 * MB);
  unsigned short* W2t  = (unsigned short*)(ws + 36 * MB);
  unsigned short* Qh   = (unsigned short*)(ws + 40 * MB);
  unsigned short* Kh   = (unsigned short*)(ws + 48 * MB);
  unsigned short* Vh   = (unsigned short*)(ws + 56 * MB);
  unsigned short* VhT  = (unsigned short*)(ws + 64 * MB);
  unsigned short* ctx  = (unsigned short*)(ws + 72 * MB);
  float*          xf   = (float*)(ws + 80 * MB);
  unsigned short* hb   = (unsigned short*)(ws + 96 * MB);
  unsigned short* tbuf = (unsigned short*)(ws + 104 * MB);

  const int n8 = B_ * N_ * C_ / 8;
  cast3_bf16<<<dim3((n8 + 255) / 256, 1, 3), 256, 0, stream>>>(q, k, v, qb, kb, vb, n8);

  dim3 blk32(32, 8);
  wt_cast4<<<dim3(C_ / 32, C_ / 32, 4), blk32, 0, stream>>>(Wq, Wk, Wv, Wo, Wqt, Wkt, Wvt, Wot);
  wt_cast<<<dim3(FF_ / 32, C_ / 32), blk32, 0, stream>>>(W1, W1t, C_, FF_);
  wt_cast<<<dim3(C_ / 32, FF_ / 32), blk32, 0, stream>>>(W2, W2t, FF_, C_);

  gemm_qkv<<<dim3(B_ * N_ / 128, C_ / 128, 3), 256, 0, stream>>>(qb, kb, vb, Wqt, Wkt, Wvt,
                                                                 bq, bk, bv, Qh, Kh, Vh);

  vh_transpose<<<dim3(N_ / 32, HD_ / 32, B_ * H_), blk32, 0, stream>>>(Vh, VhT);
  attn_fwd<<<dim3((N_ / 128) * B_ * H_), 256, 0, stream>>>(Qh, Kh, VhT, ctx);

  gemm_n64<1><<<dim3(B_ * N_ / 128, C_ / 64), 256, 0, stream>>>(ctx, Wot, bo, q, xf, nullptr,
                                                                B_ * N_, C_, C_);
  ln_kernel<<<dim3(B_ * N_), 256, 0, stream>>>(xf, lnw, lnb, hb);
  gemm_n64<2><<<dim3(B_ * N_ / 128, FF_ / 64), 256, 0, stream>>>(hb, W1t, b1, nullptr, nullptr, tbuf,
                                                                 B_ * N_, FF_, C_);
  gemm_n64<1><<<dim3(B_ * N_ / 128, C_ / 64), 256, 0, stream>>>(tbuf, W2t, b2, xf, out, nullptr,
                                                                B_ * N_, C_, FF_);
}

// Round 15
// 232.291 us; speedup vs baseline: 1.0754x; 1.0754x over previous
//
#include <hip/hip_runtime.h>

constexpr int B_ = 2, N_ = 2048, C_ = 1024, H_ = 16, HD_ = 64, FF_ = 2048;

typedef __attribute__((ext_vector_type(8))) __bf16 bf16x8;
typedef __attribute__((ext_vector_type(2))) __bf16 bf16x2;
typedef __attribute__((ext_vector_type(4))) float f32x4;
typedef __attribute__((ext_vector_type(16))) float f32x16;

#define WAITVM(n) asm volatile("s_waitcnt vmcnt(" #n ")" ::: "memory")
#define WAITLGKM0 asm volatile("s_waitcnt lgkmcnt(0)" ::: "memory")

__device__ __forceinline__ unsigned short f2bf(float f) {
  union { float f; unsigned int u; } v; v.f = f;
  unsigned int r = v.u + 0x7fffu + ((v.u >> 16) & 1u);
  return (unsigned short)(r >> 16);
}

__device__ __forceinline__ unsigned pk2(float a, float b) {
  bf16x2 p;
  p[0] = (__bf16)a;
  p[1] = (__bf16)b;
  union { bf16x2 v; unsigned u; } u;
  u.v = p;
  return u.u;
}

// v_permlane32_swap_b32 D,S:  newD = {D.lo, S.lo}, newS = {D.hi, S.hi}
__device__ __forceinline__ void pl32swap(unsigned& d, unsigned& s) {
  asm volatile("v_permlane32_swap_b32 %0, %1" : "+v"(d), "+v"(s));
}

__device__ __forceinline__ void gload_lds16(const unsigned short* g, unsigned short* l) {
  __builtin_amdgcn_global_load_lds((const __attribute__((address_space(1))) void*)g,
                                   (__attribute__((address_space(3))) void*)l, 16, 0, 0);
}

// XCD-chunk swizzle (attn only)
__device__ __forceinline__ int xcd_chunk(int bid, int nwg) {
  return (bid & 7) * (nwg >> 3) + (bid >> 3);
}

// ---------------- cast f32 -> bf16, z-fused over q,k,v ----------------
__global__ __launch_bounds__(256)
void cast3_bf16(const float* __restrict__ q, const float* __restrict__ k,
                const float* __restrict__ v, unsigned short* __restrict__ qo,
                unsigned short* __restrict__ ko, unsigned short* __restrict__ vo, int n8) {
  int i = blockIdx.x * 256 + threadIdx.x;
  if (i >= n8) return;
  const float* in = blockIdx.z == 0 ? q : (blockIdx.z == 1 ? k : v);
  unsigned short* out = blockIdx.z == 0 ? qo : (blockIdx.z == 1 ? ko : vo);
  const float4 a = ((const float4*)in)[2 * i];
  const float4 b = ((const float4*)in)[2 * i + 1];
  uint4 o;
  o.x = (unsigned)f2bf(a.x) | ((unsigned)f2bf(a.y) << 16);
  o.y = (unsigned)f2bf(a.z) | ((unsigned)f2bf(a.w) << 16);
  o.z = (unsigned)f2bf(b.x) | ((unsigned)f2bf(b.y) << 16);
  o.w = (unsigned)f2bf(b.z) | ((unsigned)f2bf(b.w) << 16);
  ((uint4*)out)[i] = o;
}

// ---------------- cast+transpose weights: W[K][N] f32 -> Wt[N][K] bf16 ----------------
__global__ __launch_bounds__(256)
void wt_cast(const float* __restrict__ W, unsigned short* __restrict__ Wt, int K, int N) {
  __shared__ unsigned short tile[32][33];
  const int tx = threadIdx.x, ty = threadIdx.y;
  const int n0 = blockIdx.x * 32, k0 = blockIdx.y * 32;
#pragma unroll
  for (int r = 0; r < 4; ++r)
    tile[ty + r * 8][tx] = f2bf(W[(size_t)(k0 + ty + r * 8) * N + n0 + tx]);
  __syncthreads();
#pragma unroll
  for (int r = 0; r < 4; ++r)
    Wt[(size_t)(n0 + ty + r * 8) * K + k0 + tx] = tile[tx][ty + r * 8];
}

// z-fused version for the four C x C weights
__global__ __launch_bounds__(256)
void wt_cast4(const float* __restrict__ Wa, const float* __restrict__ Wb,
              const float* __restrict__ Wc, const float* __restrict__ Wd,
              unsigned short* __restrict__ Oa, unsigned short* __restrict__ Ob,
              unsigned short* __restrict__ Oc, unsigned short* __restrict__ Od) {
  __shared__ unsigned short tile[32][33];
  const int z = blockIdx.z;
  const float* W = z == 0 ? Wa : (z == 1 ? Wb : (z == 2 ? Wc : Wd));
  unsigned short* Wt = z == 0 ? Oa : (z == 1 ? Ob : (z == 2 ? Oc : Od));
  const int tx = threadIdx.x, ty = threadIdx.y;
  const int n0 = blockIdx.x * 32, k0 = blockIdx.y * 32;
#pragma unroll
  for (int r = 0; r < 4; ++r)
    tile[ty + r * 8][tx] = f2bf(W[(size_t)(k0 + ty + r * 8) * C_ + n0 + tx]);
  __syncthreads();
#pragma unroll
  for (int r = 0; r < 4; ++r)
    Wt[(size_t)(n0 + ty + r * 8) * C_ + k0 + tx] = tile[tx][ty + r * 8];
}

// ---------------- Vh [B,N,H,HD] -> VhT [B,H,HD,N] (bf16) ----------------
__global__ __launch_bounds__(256)
void vh_transpose(const unsigned short* __restrict__ Vh, unsigned short* __restrict__ VhT) {
  __shared__ unsigned short tile[32][33];
  const int tx = threadIdx.x, ty = threadIdx.y;
  const int bh = blockIdx.z, b = bh >> 4, h = bh & 15;
  const int n0 = blockIdx.x * 32, d0 = blockIdx.y * 32;
#pragma unroll
  for (int r = 0; r < 4; ++r) {
    int n = n0 + ty + r * 8;
    tile[ty + r * 8][tx] = Vh[((size_t)(b * N_ + n)) * C_ + h * HD_ + d0 + tx];
  }
  __syncthreads();
#pragma unroll
  for (int r = 0; r < 4; ++r) {
    int d = d0 + ty + r * 8;
    VhT[((size_t)(bh * HD_ + d)) * N_ + n0 + tx] = tile[tx][ty + r * 8];
  }
}

// ---------------- 128x128 GEMM (2-phase dbuf), z-fused QKV (out bf16) ----------------
// z==0 (Q) output pre-scaled by c1 = 1/sqrt(HD) * log2(e) for log2-domain softmax.
__global__ __launch_bounds__(256, 2)
void gemm_qkv(const unsigned short* __restrict__ A0, const unsigned short* __restrict__ A1,
              const unsigned short* __restrict__ A2, const unsigned short* __restrict__ B0,
              const unsigned short* __restrict__ B1, const unsigned short* __restrict__ B2,
              const float* __restrict__ c0, const float* __restrict__ c1v,
              const float* __restrict__ c2, unsigned short* __restrict__ O0,
              unsigned short* __restrict__ O1, unsigned short* __restrict__ O2) {
  const int z = blockIdx.z;
  const unsigned short* A = z == 0 ? A0 : (z == 1 ? A1 : A2);
  const unsigned short* Bt = z == 0 ? B0 : (z == 1 ? B1 : B2);
  const float* bias = z == 0 ? c0 : (z == 1 ? c1v : c2);
  unsigned short* outB = z == 0 ? O0 : (z == 1 ? O1 : O2);
  const float sc = z == 0 ? 0.18033688011112042f : 1.0f;
  const int K = C_, Nn = C_;

  __shared__ unsigned short lA[2][128 * 64];
  __shared__ unsigned short lB[2][128 * 64];
  const int t = threadIdx.x;
  const int lane = t & 63;
  const int w = t >> 6;
  const int wm = w >> 1, wn = w & 1;
  const int l15 = lane & 15, g = lane >> 4;

  const unsigned short* Ab = A + (size_t)blockIdx.x * 128 * K;
  const unsigned short* Bb = Bt + (size_t)blockIdx.y * 128 * K;

  auto stage = [&](int buf, int k0) {
#pragma unroll
    for (int i = 0; i < 4; ++i) {
      int id = i * 256 + t;
      gload_lds16(Ab + (size_t)(id >> 3) * K + k0 + (id & 7) * 8, &lA[buf][id * 8]);
    }
#pragma unroll
    for (int i = 0; i < 4; ++i) {
      int id = i * 256 + t;
      gload_lds16(Bb + (size_t)(id >> 3) * K + k0 + (id & 7) * 8, &lB[buf][id * 8]);
    }
  };

  f32x4 acc[4][4] = {};

  stage(0, 0);
  __syncthreads();
  int cur = 0;
  for (int k0 = 0; k0 < K; k0 += 64) {
    if (k0 + 64 < K) stage(cur ^ 1, k0 + 64);
#pragma unroll
    for (int kk = 0; kk < 2; ++kk) {
      bf16x8 af[4], bfr[4];
#pragma unroll
      for (int mi = 0; mi < 4; ++mi)
        af[mi] = *(const bf16x8*)&lA[cur][(wm * 64 + mi * 16 + l15) * 64 + kk * 32 + g * 8];
#pragma unroll
      for (int ni = 0; ni < 4; ++ni)
        bfr[ni] = *(const bf16x8*)&lB[cur][(wn * 64 + ni * 16 + l15) * 64 + kk * 32 + g * 8];
      __builtin_amdgcn_s_setprio(1);
#pragma unroll
      for (int mi = 0; mi < 4; ++mi)
#pragma unroll
        for (int ni = 0; ni < 4; ++ni)
          acc[mi][ni] = __builtin_amdgcn_mfma_f32_16x16x32_bf16(af[mi], bfr[ni], acc[mi][ni], 0, 0, 0);
      __builtin_amdgcn_s_setprio(0);
    }
    __syncthreads();
    cur ^= 1;
  }

#pragma unroll
  for (int mi = 0; mi < 4; ++mi)
#pragma unroll
    for (int ni = 0; ni < 4; ++ni) {
      const int col = blockIdx.y * 128 + wn * 64 + ni * 16 + l15;
      const float bcol = bias[col];
#pragma unroll
      for (int r = 0; r < 4; ++r) {
        const int row = blockIdx.x * 128 + wm * 64 + mi * 16 + g * 4 + r;
        outB[(size_t)row * Nn + col] = f2bf((acc[mi][ni][r] + bcol) * sc);
      }
    }
}

// ---------------- 128x128 GEMM (2-phase dbuf) with epilogues ----------------
template <int EPI>
__global__ __launch_bounds__(256, 2)
void gemm_bt(const unsigned short* __restrict__ A, const unsigned short* __restrict__ Bt,
             const float* __restrict__ bias, const float* __restrict__ resid,
             float* __restrict__ outF, unsigned short* __restrict__ outB,
             int M, int N, int K) {
  __shared__ unsigned short lA[2][128 * 64];
  __shared__ unsigned short lB[2][128 * 64];
  const int t = threadIdx.x;
  const int lane = t & 63;
  const int w = t >> 6;
  const int wm = w >> 1, wn = w & 1;
  const int l15 = lane & 15, g = lane >> 4;

  const unsigned short* Ab = A + (size_t)blockIdx.x * 128 * K;
  const unsigned short* Bb = Bt + (size_t)blockIdx.y * 128 * K;

  auto stage = [&](int buf, int k0) {
#pragma unroll
    for (int i = 0; i < 4; ++i) {
      int id = i * 256 + t;
      gload_lds16(Ab + (size_t)(id >> 3) * K + k0 + (id & 7) * 8, &lA[buf][id * 8]);
    }
#pragma unroll
    for (int i = 0; i < 4; ++i) {
      int id = i * 256 + t;
      gload_lds16(Bb + (size_t)(id >> 3) * K + k0 + (id & 7) * 8, &lB[buf][id * 8]);
    }
  };

  f32x4 acc[4][4] = {};

  stage(0, 0);
  __syncthreads();
  int cur = 0;
  for (int k0 = 0; k0 < K; k0 += 64) {
    if (k0 + 64 < K) stage(cur ^ 1, k0 + 64);
#pragma unroll
    for (int kk = 0; kk < 2; ++kk) {
      bf16x8 af[4], bfr[4];
#pragma unroll
      for (int mi = 0; mi < 4; ++mi)
        af[mi] = *(const bf16x8*)&lA[cur][(wm * 64 + mi * 16 + l15) * 64 + kk * 32 + g * 8];
#pragma unroll
      for (int ni = 0; ni < 4; ++ni)
        bfr[ni] = *(const bf16x8*)&lB[cur][(wn * 64 + ni * 16 + l15) * 64 + kk * 32 + g * 8];
      __builtin_amdgcn_s_setprio(1);
#pragma unroll
      for (int mi = 0; mi < 4; ++mi)
#pragma unroll
        for (int ni = 0; ni < 4; ++ni)
          acc[mi][ni] = __builtin_amdgcn_mfma_f32_16x16x32_bf16(af[mi], bfr[ni], acc[mi][ni], 0, 0, 0);
      __builtin_amdgcn_s_setprio(0);
    }
    __syncthreads();
    cur ^= 1;
  }

#pragma unroll
  for (int mi = 0; mi < 4; ++mi)
#pragma unroll
    for (int ni = 0; ni < 4; ++ni) {
      const int col = blockIdx.y * 128 + wn * 64 + ni * 16 + l15;
      const float bcol = bias[col];
#pragma unroll
      for (int r = 0; r < 4; ++r) {
        const int row = blockIdx.x * 128 + wm * 64 + mi * 16 + g * 4 + r;
        const size_t o = (size_t)row * N + col;
        float val = acc[mi][ni][r] + bcol;
        if (EPI == 0) {
          outB[o] = f2bf(val);
        } else if (EPI == 1) {
          outF[o] = val + resid[o];
        } else {
          float ge = 0.5f * val * (1.0f + erff(val * 0.70710678118654752f));
          outB[o] = f2bf(ge);
        }
      }
    }
}

// ---------------- 128x64-tile GEMM (2-phase dbuf; skinny N), out f32 = v+bias+resid ----------------
__global__ __launch_bounds__(256, 2)
void gemm_n64(const unsigned short* __restrict__ A, const unsigned short* __restrict__ Bt,
              const float* __restrict__ bias, const float* __restrict__ resid,
              float* __restrict__ outF, int M, int N, int K) {
  __shared__ unsigned short lA[2][128 * 64];
  __shared__ unsigned short lB[2][64 * 64];
  const int t = threadIdx.x;
  const int lane = t & 63;
  const int w = t >> 6;
  const int wm = w >> 1, wn = w & 1;
  const int l15 = lane & 15, g = lane >> 4;

  const unsigned short* Ab = A + (size_t)blockIdx.x * 128 * K;
  const unsigned short* Bb = Bt + (size_t)blockIdx.y * 64 * K;

  auto stage = [&](int buf, int k0) {
#pragma unroll
    for (int i = 0; i < 4; ++i) {
      int id = i * 256 + t;
      gload_lds16(Ab + (size_t)(id >> 3) * K + k0 + (id & 7) * 8, &lA[buf][id * 8]);
    }
#pragma unroll
    for (int i = 0; i < 2; ++i) {
      int id = i * 256 + t;
      gload_lds16(Bb + (size_t)(id >> 3) * K + k0 + (id & 7) * 8, &lB[buf][id * 8]);
    }
  };

  f32x4 acc[4][2] = {};

  stage(0, 0);
  __syncthreads();
  int cur = 0;
  for (int k0 = 0; k0 < K; k0 += 64) {
    if (k0 + 64 < K) stage(cur ^ 1, k0 + 64);
#pragma unroll
    for (int kk = 0; kk < 2; ++kk) {
      bf16x8 af[4], bfr[2];
#pragma unroll
      for (int mi = 0; mi < 4; ++mi)
        af[mi] = *(const bf16x8*)&lA[cur][(wm * 64 + mi * 16 + l15) * 64 + kk * 32 + g * 8];
#pragma unroll
      for (int ni = 0; ni < 2; ++ni)
        bfr[ni] = *(const bf16x8*)&lB[cur][(wn * 32 + ni * 16 + l15) * 64 + kk * 32 + g * 8];
      __builtin_amdgcn_s_setprio(1);
#pragma unroll
      for (int mi = 0; mi < 4; ++mi)
#pragma unroll
        for (int ni = 0; ni < 2; ++ni)
          acc[mi][ni] = __builtin_amdgcn_mfma_f32_16x16x32_bf16(af[mi], bfr[ni], acc[mi][ni], 0, 0, 0);
      __builtin_amdgcn_s_setprio(0);
    }
    __syncthreads();
    cur ^= 1;
  }

#pragma unroll
  for (int mi = 0; mi < 4; ++mi)
#pragma unroll
    for (int ni = 0; ni < 2; ++ni) {
      const int col = blockIdx.y * 64 + wn * 32 + ni * 16 + l15;
      const float bcol = bias[col];
#pragma unroll
      for (int r = 0; r < 4; ++r) {
        const int row = blockIdx.x * 128 + wm * 64 + mi * 16 + g * 4 + r;
        const size_t o = (size_t)row * N + col;
        outF[o] = acc[mi][ni][r] + bcol + resid[o];
      }
    }
}

// ---------------- flash attention (r13-best: 32x32 MFMA + permlane32_swap) ----------------
// 512 blocks (XCD-chunk swizzled), 256 threads = 4 waves, 32 q-rows per wave.
// QK^T: S^T = mfma_32x32x16(K_frag, Q_frag); P repack via v_permlane32_swap;
// PV: mfma_32x32x16(V^T, P). K/V LDS XOR-swizzled, counted vmcnt.
// Q pre-scaled by c1 -> S in log2 units.
__global__ __launch_bounds__(256, 2)
void attn_fwd(const unsigned short* __restrict__ Qh, const unsigned short* __restrict__ Kh,
              const unsigned short* __restrict__ VhT, unsigned short* __restrict__ ctx) {
  __shared__ unsigned short lK[2][64 * 64];
  __shared__ unsigned short lV[2][64 * 64];

  const int t = threadIdx.x, lane = t & 63, w = t >> 6;
  const int l31 = lane & 31, hl = lane >> 5;
  const int swz = xcd_chunk(blockIdx.x, (N_ / 128) * B_ * H_);
  const int bx = swz & (N_ / 128 - 1), bh = swz >> 4;
  const int b = bh >> 4, h = bh & 15;
  const int qb0 = bx * 128 + w * 32;

  const unsigned short* Qb = Qh + (size_t)b * N_ * C_ + h * HD_;
  const unsigned short* Kb = Kh + (size_t)b * N_ * C_ + h * HD_;
  const unsigned short* Vb = VhT + (size_t)bh * HD_ * N_;

  // Q frags (B-operand): lane holds Q[q = qb0+l31][d = f*16 + hl*8 + j]
  bf16x8 qf[4];
#pragma unroll
  for (int f = 0; f < 4; ++f)
    qf[f] = *(const bf16x8*)(Qb + (size_t)(qb0 + l31) * C_ + f * 16 + hl * 8);

  // stage: linear LDS dest, inverse-swizzled global source (rule #21)
  auto stageK = [&](int buf, int kb) {
#pragma unroll
    for (int i = 0; i < 2; ++i) {
      int o = (i * 256 + t) * 16;                 // tile byte offset
      int r = o >> 7;                             // row (key)
      int c = (o & 127) ^ ((r & 7) << 4);         // swizzled byte col
      gload_lds16(Kb + (size_t)(kb + r) * C_ + (c >> 1), &lK[buf][o >> 1]);
    }
  };
  auto stageV = [&](int buf, int kb) {
#pragma unroll
    for (int i = 0; i < 2; ++i) {
      int o = (i * 256 + t) * 16;
      int r = o >> 7;                             // row (d)
      int c = (o & 127) ^ ((r & 7) << 4);
      gload_lds16(Vb + (size_t)r * N_ + kb + (c >> 1), &lV[buf][o >> 1]);
    }
  };

  f32x16 od[2] = {};
  float mrun = -1e30f;
  float srun = 0.f;
  const float DTHR = 11.541560327111707f;  // 8 * log2(e)
  const int NT = N_ / 64;
  const int sw = (l31 & 7) << 4;           // byte-swizzle for LDS reads

  stageK(0, 0);
  stageV(0, 0);

  int cur = 0;
  for (int tile = 0; tile < NT; ++tile) {
    if (tile + 1 < NT) {
      stageK(cur ^ 1, (tile + 1) * 64);
      stageV(cur ^ 1, (tile + 1) * 64);
      WAITVM(4);            // current tile staged; next tile's 4 loads in flight
    } else {
      WAITVM(0);
    }
    __builtin_amdgcn_s_barrier();

    // ---- QK^T: S^T[key][q] per 32-key block ----
    f32x16 st[2];
    __builtin_amdgcn_s_setprio(1);
#pragma unroll
    for (int kb2 = 0; kb2 < 2; ++kb2) {
      f32x16 z = {};
#pragma unroll
      for (int f = 0; f < 4; ++f) {
        const int byt = (kb2 * 32 + l31) * 128 + ((f * 32 + hl * 16) ^ sw);
        const bf16x8 ka = *(const bf16x8*)&lK[cur][byt >> 1];
        z = __builtin_amdgcn_mfma_f32_32x32x16_bf16(ka, qf[f], z, 0, 0, 0);
      }
      st[kb2] = z;
    }
    __builtin_amdgcn_s_setprio(0);

    // ---- online softmax (log2 domain) with defer-max ----
    float mx = st[0][0];
#pragma unroll
    for (int r = 1; r < 16; ++r) mx = fmaxf(mx, st[0][r]);
#pragma unroll
    for (int r = 0; r < 16; ++r) mx = fmaxf(mx, st[1][r]);
    mx = fmaxf(mx, __shfl_xor(mx, 32));
    if (__any(mx > mrun + DTHR)) {
      const float mn = fmaxf(mrun, mx);
      const float sf = exp2f(mrun - mn);
      mrun = mn;
      srun *= sf;
#pragma unroll
      for (int dblk = 0; dblk < 2; ++dblk)
#pragma unroll
        for (int r = 0; r < 16; ++r) od[dblk][r] *= sf;
    }

    // ---- P = exp2(S - m), repack to PV B-fragments via permlane32_swap ----
    bf16x8 pb[4];
#pragma unroll
    for (int kb2 = 0; kb2 < 2; ++kb2) {
      float p[16];
#pragma unroll
      for (int r = 0; r < 16; ++r) {
        p[r] = exp2f(st[kb2][r] - mrun);
        srun += p[r];
      }
      unsigned qd[8];
#pragma unroll
      for (int i = 0; i < 8; ++i) qd[i] = pk2(p[2 * i], p[2 * i + 1]);
      pl32swap(qd[0], qd[2]);
      pl32swap(qd[1], qd[3]);
      pl32swap(qd[4], qd[6]);
      pl32swap(qd[5], qd[7]);
      union { unsigned u[4]; bf16x8 v; } f0, f1;
      f0.u[0] = qd[0];
      f0.u[1] = qd[1];
      f0.u[2] = qd[2];
      f0.u[3] = qd[3];
      f1.u[0] = qd[4];
      f1.u[1] = qd[5];
      f1.u[2] = qd[6];
      f1.u[3] = qd[7];
      pb[kb2 * 2 + 0] = f0.v;
      pb[kb2 * 2 + 1] = f1.v;
    }

    // ---- PV: O^T += V^T * P ----
    __builtin_amdgcn_s_setprio(1);
#pragma unroll
    for (int dblk = 0; dblk < 2; ++dblk) {
#pragma unroll
      for (int kf = 0; kf < 4; ++kf) {
        const int byt = (dblk * 32 + l31) * 128 + ((kf * 32 + hl * 16) ^ sw);
        const bf16x8 va = *(const bf16x8*)&lV[cur][byt >> 1];
        od[dblk] = __builtin_amdgcn_mfma_f32_32x32x16_bf16(va, pb[kf], od[dblk], 0, 0, 0);
      }
    }
    __builtin_amdgcn_s_setprio(0);

    WAITLGKM0;              // own LDS reads retired before buffer overwrite
    __builtin_amdgcn_s_barrier();
    cur ^= 1;
  }

  float s = srun + __shfl_xor(srun, 32);
  const float rinv = 1.0f / s;
  unsigned short* cp = ctx + ((size_t)(b * N_ + qb0 + l31)) * C_ + h * HD_;
#pragma unroll
  for (int dblk = 0; dblk < 2; ++dblk)
#pragma unroll
    for (int a = 0; a < 4; ++a) {
      const int r0 = a * 4;
      uint2 o;
      o.x = pk2(od[dblk][r0] * rinv, od[dblk][r0 + 1] * rinv);
      o.y = pk2(od[dblk][r0 + 2] * rinv, od[dblk][r0 + 3] * rinv);
      *(uint2*)(cp + dblk * 32 + a * 8 + hl * 4) = o;
    }
}

// ---------------- LayerNorm: x f32 [BN, C] -> h bf16, wave-per-row ----------------
// 256 threads = 4 waves = 4 rows per block; pure shuffle reduce, no LDS/barriers.
__global__ __launch_bounds__(256)
void ln_kernel(const float* __restrict__ x, const float* __restrict__ lw,
               const float* __restrict__ lb, unsigned short* __restrict__ h) {
  const int w = threadIdx.x >> 6, lane = threadIdx.x & 63;
  const int row = blockIdx.x * 4 + w;
  const float4* xr = (const float4*)(x + (size_t)row * C_);
  float4 v[4];
  float sum = 0.f;
#pragma unroll
  for (int i = 0; i < 4; ++i) {
    v[i] = xr[lane + i * 64];
    sum += (v[i].x + v[i].y) + (v[i].z + v[i].w);
  }
#pragma unroll
  for (int m = 1; m < 64; m <<= 1) sum += __shfl_xor(sum, m);
  const float mu = sum * (1.0f / C_);
  float sq = 0.f;
#pragma unroll
  for (int i = 0; i < 4; ++i) {
    const float d0 = v[i].x - mu, d1 = v[i].y - mu, d2 = v[i].z - mu, d3 = v[i].w - mu;
    sq += (d0 * d0 + d1 * d1) + (d2 * d2 + d3 * d3);
  }
#pragma unroll
  for (int m = 1; m < 64; m <<= 1) sq += __shfl_xor(sq, m);
  const float rstd = rsqrtf(sq * (1.0f / C_) + 1e-5f);
  uint2* ho = (uint2*)(h + (size_t)row * C_);
#pragma unroll
  for (int i = 0; i < 4; ++i) {
    const float4 ww = ((const float4*)lw)[lane + i * 64];
    const float4 bb = ((const float4*)lb)[lane + i * 64];
    uint2 o;
    o.x = pk2((v[i].x - mu) * rstd * ww.x + bb.x, (v[i].y - mu) * rstd * ww.y + bb.y);
    o.y = pk2((v[i].z - mu) * rstd * ww.z + bb.z, (v[i].w - mu) * rstd * ww.w + bb.w);
    ho[lane + i * 64] = o;
  }
}

extern "C" void kernel_launch(void* const* d_in, const int* in_sizes, int n_in,
                              void* d_out, int out_size, void* d_ws, size_t ws_size,
                              hipStream_t stream) {
  const float* q   = (const float*)d_in[0];
  const float* k   = (const float*)d_in[1];
  const float* v   = (const float*)d_in[2];
  const float* Wq  = (const float*)d_in[3];
  const float* bq  = (const float*)d_in[4];
  const float* Wk  = (const float*)d_in[5];
  const float* bk  = (const float*)d_in[6];
  const float* Wv  = (const float*)d_in[7];
  const float* bv  = (const float*)d_in[8];
  const float* Wo  = (const float*)d_in[9];
  const float* bo  = (const float*)d_in[10];
  const float* lnw = (const float*)d_in[11];
  const float* lnb = (const float*)d_in[12];
  const float* W1  = (const float*)d_in[13];
  const float* b1  = (const float*)d_in[14];
  const float* W2  = (const float*)d_in[15];
  const float* b2  = (const float*)d_in[16];
  float* out = (float*)d_out;

  char* ws = (char*)d_ws;
  const size_t MB = 1024 * 1024;
  if (ws_size < 120 * MB) return;
  unsigned short* qb   = (unsigned short*)(ws + 0 * MB);
  unsigned short* kb   = (unsigned short*)(ws + 8 * MB);
  unsigned short* vb   = (unsigned short*)(ws + 16 * MB);
  unsigned short* Wqt  = (unsigned short*)(ws + 24 * MB);
  unsigned short* Wkt  = (unsigned short*)(ws + 26 * MB);
  unsigned short* Wvt  = (unsigned short*)(ws + 28 * MB);
  unsigned short* Wot  = (unsigned short*)(ws + 30 * MB);
  unsigned short* W1t  = (unsigned short*)(ws + 32 * MB);
  unsigned short* W2t  = (unsigned short*)(ws + 36 * MB);
  unsigned short* Qh   = (unsigned short*)(ws + 40 * MB);
  unsigned short* Kh   = (unsigned short*)(ws + 48 * MB);
  unsigned short* Vh   = (unsigned short*)(ws + 56 * MB);
  unsigned short* VhT  = (unsigned short*)(ws + 64 * MB);
  unsigned short* ctx  = (unsigned short*)(ws + 72 * MB);
  float*          xf   = (float*)(ws + 80 * MB);
  unsigned short* hb   = (unsigned short*)(ws + 96 * MB);
  unsigned short* tbuf = (unsigned short*)(ws + 104 * MB);

  const int n8 = B_ * N_ * C_ / 8;
  cast3_bf16<<<dim3((n8 + 255) / 256, 1, 3), 256, 0, stream>>>(q, k, v, qb, kb, vb, n8);

  dim3 blk32(32, 8);
  wt_cast4<<<dim3(C_ / 32, C_ / 32, 4), blk32, 0, stream>>>(Wq, Wk, Wv, Wo, Wqt, Wkt, Wvt, Wot);
  wt_cast<<<dim3(FF_ / 32, C_ / 32), blk32, 0, stream>>>(W1, W1t, C_, FF_);
  wt_cast<<<dim3(C_ / 32, FF_ / 32), blk32, 0, stream>>>(W2, W2t, FF_, C_);

  gemm_qkv<<<dim3(B_ * N_ / 128, C_ / 128, 3), 256, 0, stream>>>(qb, kb, vb, Wqt, Wkt, Wvt,
                                                                 bq, bk, bv, Qh, Kh, Vh);

  vh_transpose<<<dim3(N_ / 32, HD_ / 32, B_ * H_), blk32, 0, stream>>>(Vh, VhT);
  attn_fwd<<<dim3((N_ / 128) * B_ * H_), 256, 0, stream>>>(Qh, Kh, VhT, ctx);

  gemm_n64<<<dim3(B_ * N_ / 128, C_ / 64), 256, 0, stream>>>(ctx, Wot, bo, q, xf, B_ * N_, C_, C_);
  ln_kernel<<<dim3(B_ * N_ / 4), 256, 0, stream>>>(xf, lnw, lnb, hb);
  gemm_bt<2><<<dim3(B_ * N_ / 128, FF_ / 128), 256, 0, stream>>>(hb, W1t, b1, nullptr, nullptr, tbuf,
                                                                 B_ * N_, FF_, C_);
  gemm_n64<<<dim3(B_ * N_ / 128, C_ / 64), 256, 0, stream>>>(tbuf, W2t, b2, xf, out, B_ * N_, C_, FF_);
}

// Round 16
// 229.685 us; speedup vs baseline: 1.0876x; 1.0113x over previous
//
#include <hip/hip_runtime.h>

constexpr int B_ = 2, N_ = 2048, C_ = 1024, H_ = 16, HD_ = 64, FF_ = 2048;

typedef __attribute__((ext_vector_type(8))) __bf16 bf16x8;
typedef __attribute__((ext_vector_type(2))) __bf16 bf16x2;
typedef __attribute__((ext_vector_type(4))) float f32x4;
typedef __attribute__((ext_vector_type(16))) float f32x16;

#define WAITVM(n) asm volatile("s_waitcnt vmcnt(" #n ")" ::: "memory")
#define WAITLGKM0 asm volatile("s_waitcnt lgkmcnt(0)" ::: "memory")

__device__ __forceinline__ unsigned short f2bf(float f) {
  union { float f; unsigned int u; } v; v.f = f;
  unsigned int r = v.u + 0x7fffu + ((v.u >> 16) & 1u);
  return (unsigned short)(r >> 16);
}

__device__ __forceinline__ float bf2f(unsigned short u) {
  union { unsigned v; float f; } c;
  c.v = (unsigned)u << 16;
  return c.f;
}

__device__ __forceinline__ unsigned pk2(float a, float b) {
  bf16x2 p;
  p[0] = (__bf16)a;
  p[1] = (__bf16)b;
  union { bf16x2 v; unsigned u; } u;
  u.v = p;
  return u.u;
}

// v_permlane32_swap_b32 D,S:  newD = {D.lo, S.lo}, newS = {D.hi, S.hi}
__device__ __forceinline__ void pl32swap(unsigned& d, unsigned& s) {
  asm volatile("v_permlane32_swap_b32 %0, %1" : "+v"(d), "+v"(s));
}

__device__ __forceinline__ void gload_lds16(const unsigned short* g, unsigned short* l) {
  __builtin_amdgcn_global_load_lds((const __attribute__((address_space(1))) void*)g,
                                   (__attribute__((address_space(3))) void*)l, 16, 0, 0);
}

// XCD-chunk swizzle (attn only)
__device__ __forceinline__ int xcd_chunk(int bid, int nwg) {
  return (bid & 7) * (nwg >> 3) + (bid >> 3);
}

// ---------------- cast f32 -> bf16, z-fused over q,k,v ----------------
__global__ __launch_bounds__(256)
void cast3_bf16(const float* __restrict__ q, const float* __restrict__ k,
                const float* __restrict__ v, unsigned short* __restrict__ qo,
                unsigned short* __restrict__ ko, unsigned short* __restrict__ vo, int n8) {
  int i = blockIdx.x * 256 + threadIdx.x;
  if (i >= n8) return;
  const float* in = blockIdx.z == 0 ? q : (blockIdx.z == 1 ? k : v);
  unsigned short* out = blockIdx.z == 0 ? qo : (blockIdx.z == 1 ? ko : vo);
  const float4 a = ((const float4*)in)[2 * i];
  const float4 b = ((const float4*)in)[2 * i + 1];
  uint4 o;
  o.x = (unsigned)f2bf(a.x) | ((unsigned)f2bf(a.y) << 16);
  o.y = (unsigned)f2bf(a.z) | ((unsigned)f2bf(a.w) << 16);
  o.z = (unsigned)f2bf(b.x) | ((unsigned)f2bf(b.y) << 16);
  o.w = (unsigned)f2bf(b.z) | ((unsigned)f2bf(b.w) << 16);
  ((uint4*)out)[i] = o;
}

// ---------------- cast+transpose weights: W[K][N] f32 -> Wt[N][K] bf16 ----------------
__global__ __launch_bounds__(256)
void wt_cast(const float* __restrict__ W, unsigned short* __restrict__ Wt, int K, int N) {
  __shared__ unsigned short tile[32][33];
  const int tx = threadIdx.x, ty = threadIdx.y;
  const int n0 = blockIdx.x * 32, k0 = blockIdx.y * 32;
#pragma unroll
  for (int r = 0; r < 4; ++r)
    tile[ty + r * 8][tx] = f2bf(W[(size_t)(k0 + ty + r * 8) * N + n0 + tx]);
  __syncthreads();
#pragma unroll
  for (int r = 0; r < 4; ++r)
    Wt[(size_t)(n0 + ty + r * 8) * K + k0 + tx] = tile[tx][ty + r * 8];
}

// z-fused version for the four C x C weights
__global__ __launch_bounds__(256)
void wt_cast4(const float* __restrict__ Wa, const float* __restrict__ Wb,
              const float* __restrict__ Wc, const float* __restrict__ Wd,
              unsigned short* __restrict__ Oa, unsigned short* __restrict__ Ob,
              unsigned short* __restrict__ Oc, unsigned short* __restrict__ Od) {
  __shared__ unsigned short tile[32][33];
  const int z = blockIdx.z;
  const float* W = z == 0 ? Wa : (z == 1 ? Wb : (z == 2 ? Wc : Wd));
  unsigned short* Wt = z == 0 ? Oa : (z == 1 ? Ob : (z == 2 ? Oc : Od));
  const int tx = threadIdx.x, ty = threadIdx.y;
  const int n0 = blockIdx.x * 32, k0 = blockIdx.y * 32;
#pragma unroll
  for (int r = 0; r < 4; ++r)
    tile[ty + r * 8][tx] = f2bf(W[(size_t)(k0 + ty + r * 8) * C_ + n0 + tx]);
  __syncthreads();
#pragma unroll
  for (int r = 0; r < 4; ++r)
    Wt[(size_t)(n0 + ty + r * 8) * C_ + k0 + tx] = tile[tx][ty + r * 8];
}

// ---------------- Vh [B,N,H,HD] -> VhT [B,H,HD,N] (bf16) ----------------
__global__ __launch_bounds__(256)
void vh_transpose(const unsigned short* __restrict__ Vh, unsigned short* __restrict__ VhT) {
  __shared__ unsigned short tile[32][33];
  const int tx = threadIdx.x, ty = threadIdx.y;
  const int bh = blockIdx.z, b = bh >> 4, h = bh & 15;
  const int n0 = blockIdx.x * 32, d0 = blockIdx.y * 32;
#pragma unroll
  for (int r = 0; r < 4; ++r) {
    int n = n0 + ty + r * 8;
    tile[ty + r * 8][tx] = Vh[((size_t)(b * N_ + n)) * C_ + h * HD_ + d0 + tx];
  }
  __syncthreads();
#pragma unroll
  for (int r = 0; r < 4; ++r) {
    int d = d0 + ty + r * 8;
    VhT[((size_t)(bh * HD_ + d)) * N_ + n0 + tx] = tile[tx][ty + r * 8];
  }
}

// ---------------- 128x128 GEMM (2-phase dbuf), z-fused QKV (out bf16) ----------------
// z==0 (Q) output pre-scaled by c1 = 1/sqrt(HD) * log2(e) for log2-domain softmax.
__global__ __launch_bounds__(256, 2)
void gemm_qkv(const unsigned short* __restrict__ A0, const unsigned short* __restrict__ A1,
              const unsigned short* __restrict__ A2, const unsigned short* __restrict__ B0,
              const unsigned short* __restrict__ B1, const unsigned short* __restrict__ B2,
              const float* __restrict__ c0, const float* __restrict__ c1v,
              const float* __restrict__ c2, unsigned short* __restrict__ O0,
              unsigned short* __restrict__ O1, unsigned short* __restrict__ O2) {
  const int z = blockIdx.z;
  const unsigned short* A = z == 0 ? A0 : (z == 1 ? A1 : A2);
  const unsigned short* Bt = z == 0 ? B0 : (z == 1 ? B1 : B2);
  const float* bias = z == 0 ? c0 : (z == 1 ? c1v : c2);
  unsigned short* outB = z == 0 ? O0 : (z == 1 ? O1 : O2);
  const float sc = z == 0 ? 0.18033688011112042f : 1.0f;
  const int K = C_, Nn = C_;

  __shared__ unsigned short lA[2][128 * 64];
  __shared__ unsigned short lB[2][128 * 64];
  const int t = threadIdx.x;
  const int lane = t & 63;
  const int w = t >> 6;
  const int wm = w >> 1, wn = w & 1;
  const int l15 = lane & 15, g = lane >> 4;

  const unsigned short* Ab = A + (size_t)blockIdx.x * 128 * K;
  const unsigned short* Bb = Bt + (size_t)blockIdx.y * 128 * K;

  auto stage = [&](int buf, int k0) {
#pragma unroll
    for (int i = 0; i < 4; ++i) {
      int id = i * 256 + t;
      gload_lds16(Ab + (size_t)(id >> 3) * K + k0 + (id & 7) * 8, &lA[buf][id * 8]);
    }
#pragma unroll
    for (int i = 0; i < 4; ++i) {
      int id = i * 256 + t;
      gload_lds16(Bb + (size_t)(id >> 3) * K + k0 + (id & 7) * 8, &lB[buf][id * 8]);
    }
  };

  f32x4 acc[4][4] = {};

  stage(0, 0);
  __syncthreads();
  int cur = 0;
  for (int k0 = 0; k0 < K; k0 += 64) {
    if (k0 + 64 < K) stage(cur ^ 1, k0 + 64);
#pragma unroll
    for (int kk = 0; kk < 2; ++kk) {
      bf16x8 af[4], bfr[4];
#pragma unroll
      for (int mi = 0; mi < 4; ++mi)
        af[mi] = *(const bf16x8*)&lA[cur][(wm * 64 + mi * 16 + l15) * 64 + kk * 32 + g * 8];
#pragma unroll
      for (int ni = 0; ni < 4; ++ni)
        bfr[ni] = *(const bf16x8*)&lB[cur][(wn * 64 + ni * 16 + l15) * 64 + kk * 32 + g * 8];
      __builtin_amdgcn_s_setprio(1);
#pragma unroll
      for (int mi = 0; mi < 4; ++mi)
#pragma unroll
        for (int ni = 0; ni < 4; ++ni)
          acc[mi][ni] = __builtin_amdgcn_mfma_f32_16x16x32_bf16(af[mi], bfr[ni], acc[mi][ni], 0, 0, 0);
      __builtin_amdgcn_s_setprio(0);
    }
    __syncthreads();
    cur ^= 1;
  }

#pragma unroll
  for (int mi = 0; mi < 4; ++mi)
#pragma unroll
    for (int ni = 0; ni < 4; ++ni) {
      const int col = blockIdx.y * 128 + wn * 64 + ni * 16 + l15;
      const float bcol = bias[col];
#pragma unroll
      for (int r = 0; r < 4; ++r) {
        const int row = blockIdx.x * 128 + wm * 64 + mi * 16 + g * 4 + r;
        outB[(size_t)row * Nn + col] = f2bf((acc[mi][ni][r] + bcol) * sc);
      }
    }
}

// ---------------- 128x128 GEMM (2-phase dbuf) with epilogues ----------------
template <int EPI>
__global__ __launch_bounds__(256, 2)
void gemm_bt(const unsigned short* __restrict__ A, const unsigned short* __restrict__ Bt,
             const float* __restrict__ bias, const float* __restrict__ resid,
             float* __restrict__ outF, unsigned short* __restrict__ outB,
             int M, int N, int K) {
  __shared__ unsigned short lA[2][128 * 64];
  __shared__ unsigned short lB[2][128 * 64];
  const int t = threadIdx.x;
  const int lane = t & 63;
  const int w = t >> 6;
  const int wm = w >> 1, wn = w & 1;
  const int l15 = lane & 15, g = lane >> 4;

  const unsigned short* Ab = A + (size_t)blockIdx.x * 128 * K;
  const unsigned short* Bb = Bt + (size_t)blockIdx.y * 128 * K;

  auto stage = [&](int buf, int k0) {
#pragma unroll
    for (int i = 0; i < 4; ++i) {
      int id = i * 256 + t;
      gload_lds16(Ab + (size_t)(id >> 3) * K + k0 + (id & 7) * 8, &lA[buf][id * 8]);
    }
#pragma unroll
    for (int i = 0; i < 4; ++i) {
      int id = i * 256 + t;
      gload_lds16(Bb + (size_t)(id >> 3) * K + k0 + (id & 7) * 8, &lB[buf][id * 8]);
    }
  };

  f32x4 acc[4][4] = {};

  stage(0, 0);
  __syncthreads();
  int cur = 0;
  for (int k0 = 0; k0 < K; k0 += 64) {
    if (k0 + 64 < K) stage(cur ^ 1, k0 + 64);
#pragma unroll
    for (int kk = 0; kk < 2; ++kk) {
      bf16x8 af[4], bfr[4];
#pragma unroll
      for (int mi = 0; mi < 4; ++mi)
        af[mi] = *(const bf16x8*)&lA[cur][(wm * 64 + mi * 16 + l15) * 64 + kk * 32 + g * 8];
#pragma unroll
      for (int ni = 0; ni < 4; ++ni)
        bfr[ni] = *(const bf16x8*)&lB[cur][(wn * 64 + ni * 16 + l15) * 64 + kk * 32 + g * 8];
      __builtin_amdgcn_s_setprio(1);
#pragma unroll
      for (int mi = 0; mi < 4; ++mi)
#pragma unroll
        for (int ni = 0; ni < 4; ++ni)
          acc[mi][ni] = __builtin_amdgcn_mfma_f32_16x16x32_bf16(af[mi], bfr[ni], acc[mi][ni], 0, 0, 0);
      __builtin_amdgcn_s_setprio(0);
    }
    __syncthreads();
    cur ^= 1;
  }

#pragma unroll
  for (int mi = 0; mi < 4; ++mi)
#pragma unroll
    for (int ni = 0; ni < 4; ++ni) {
      const int col = blockIdx.y * 128 + wn * 64 + ni * 16 + l15;
      const float bcol = bias[col];
#pragma unroll
      for (int r = 0; r < 4; ++r) {
        const int row = blockIdx.x * 128 + wm * 64 + mi * 16 + g * 4 + r;
        const size_t o = (size_t)row * N + col;
        float val = acc[mi][ni][r] + bcol;
        if (EPI == 0) {
          outB[o] = f2bf(val);
        } else if (EPI == 1) {
          outF[o] = val + resid[o];
        } else {
          float ge = 0.5f * val * (1.0f + erff(val * 0.70710678118654752f));
          outB[o] = f2bf(ge);
        }
      }
    }
}

// ---------------- 128x64-tile GEMM (2-phase dbuf; skinny N) ----------------
// MODE 0: resid f32 (q), out bf16 = val + bias + resid   (o-proj -> xfb)
// MODE 1: resid bf16 (xfb), out f32 = val + bias + resid (ffn-down -> d_out)
template <int MODE>
__global__ __launch_bounds__(256, 2)
void gemm_n64(const unsigned short* __restrict__ A, const unsigned short* __restrict__ Bt,
              const float* __restrict__ bias, const void* __restrict__ residv,
              float* __restrict__ outF, unsigned short* __restrict__ outB,
              int M, int N, int K) {
  __shared__ unsigned short lA[2][128 * 64];
  __shared__ unsigned short lB[2][64 * 64];
  const int t = threadIdx.x;
  const int lane = t & 63;
  const int w = t >> 6;
  const int wm = w >> 1, wn = w & 1;
  const int l15 = lane & 15, g = lane >> 4;

  const unsigned short* Ab = A + (size_t)blockIdx.x * 128 * K;
  const unsigned short* Bb = Bt + (size_t)blockIdx.y * 64 * K;

  auto stage = [&](int buf, int k0) {
#pragma unroll
    for (int i = 0; i < 4; ++i) {
      int id = i * 256 + t;
      gload_lds16(Ab + (size_t)(id >> 3) * K + k0 + (id & 7) * 8, &lA[buf][id * 8]);
    }
#pragma unroll
    for (int i = 0; i < 2; ++i) {
      int id = i * 256 + t;
      gload_lds16(Bb + (size_t)(id >> 3) * K + k0 + (id & 7) * 8, &lB[buf][id * 8]);
    }
  };

  f32x4 acc[4][2] = {};

  stage(0, 0);
  __syncthreads();
  int cur = 0;
  for (int k0 = 0; k0 < K; k0 += 64) {
    if (k0 + 64 < K) stage(cur ^ 1, k0 + 64);
#pragma unroll
    for (int kk = 0; kk < 2; ++kk) {
      bf16x8 af[4], bfr[2];
#pragma unroll
      for (int mi = 0; mi < 4; ++mi)
        af[mi] = *(const bf16x8*)&lA[cur][(wm * 64 + mi * 16 + l15) * 64 + kk * 32 + g * 8];
#pragma unroll
      for (int ni = 0; ni < 2; ++ni)
        bfr[ni] = *(const bf16x8*)&lB[cur][(wn * 32 + ni * 16 + l15) * 64 + kk * 32 + g * 8];
      __builtin_amdgcn_s_setprio(1);
#pragma unroll
      for (int mi = 0; mi < 4; ++mi)
#pragma unroll
        for (int ni = 0; ni < 2; ++ni)
          acc[mi][ni] = __builtin_amdgcn_mfma_f32_16x16x32_bf16(af[mi], bfr[ni], acc[mi][ni], 0, 0, 0);
      __builtin_amdgcn_s_setprio(0);
    }
    __syncthreads();
    cur ^= 1;
  }

#pragma unroll
  for (int mi = 0; mi < 4; ++mi)
#pragma unroll
    for (int ni = 0; ni < 2; ++ni) {
      const int col = blockIdx.y * 64 + wn * 32 + ni * 16 + l15;
      const float bcol = bias[col];
#pragma unroll
      for (int r = 0; r < 4; ++r) {
        const int row = blockIdx.x * 128 + wm * 64 + mi * 16 + g * 4 + r;
        const size_t o = (size_t)row * N + col;
        const float val = acc[mi][ni][r] + bcol;
        if (MODE == 0) {
          const float* resid = (const float*)residv;
          outB[o] = f2bf(val + resid[o]);
        } else {
          const unsigned short* resid = (const unsigned short*)residv;
          outF[o] = val + bf2f(resid[o]);
        }
      }
    }
}

// ---------------- flash attention (r13-best: 32x32 MFMA + permlane32_swap) ----------------
// 512 blocks (XCD-chunk swizzled), 256 threads = 4 waves, 32 q-rows per wave.
// QK^T: S^T = mfma_32x32x16(K_frag, Q_frag); P repack via v_permlane32_swap;
// PV: mfma_32x32x16(V^T, P). K/V LDS XOR-swizzled, counted vmcnt.
// Q pre-scaled by c1 -> S in log2 units.
__global__ __launch_bounds__(256, 2)
void attn_fwd(const unsigned short* __restrict__ Qh, const unsigned short* __restrict__ Kh,
              const unsigned short* __restrict__ VhT, unsigned short* __restrict__ ctx) {
  __shared__ unsigned short lK[2][64 * 64];
  __shared__ unsigned short lV[2][64 * 64];

  const int t = threadIdx.x, lane = t & 63, w = t >> 6;
  const int l31 = lane & 31, hl = lane >> 5;
  const int swz = xcd_chunk(blockIdx.x, (N_ / 128) * B_ * H_);
  const int bx = swz & (N_ / 128 - 1), bh = swz >> 4;
  const int b = bh >> 4, h = bh & 15;
  const int qb0 = bx * 128 + w * 32;

  const unsigned short* Qb = Qh + (size_t)b * N_ * C_ + h * HD_;
  const unsigned short* Kb = Kh + (size_t)b * N_ * C_ + h * HD_;
  const unsigned short* Vb = VhT + (size_t)bh * HD_ * N_;

  // Q frags (B-operand): lane holds Q[q = qb0+l31][d = f*16 + hl*8 + j]
  bf16x8 qf[4];
#pragma unroll
  for (int f = 0; f < 4; ++f)
    qf[f] = *(const bf16x8*)(Qb + (size_t)(qb0 + l31) * C_ + f * 16 + hl * 8);

  // stage: linear LDS dest, inverse-swizzled global source (rule #21)
  auto stageK = [&](int buf, int kb) {
#pragma unroll
    for (int i = 0; i < 2; ++i) {
      int o = (i * 256 + t) * 16;                 // tile byte offset
      int r = o >> 7;                             // row (key)
      int c = (o & 127) ^ ((r & 7) << 4);         // swizzled byte col
      gload_lds16(Kb + (size_t)(kb + r) * C_ + (c >> 1), &lK[buf][o >> 1]);
    }
  };
  auto stageV = [&](int buf, int kb) {
#pragma unroll
    for (int i = 0; i < 2; ++i) {
      int o = (i * 256 + t) * 16;
      int r = o >> 7;                             // row (d)
      int c = (o & 127) ^ ((r & 7) << 4);
      gload_lds16(Vb + (size_t)r * N_ + kb + (c >> 1), &lV[buf][o >> 1]);
    }
  };

  f32x16 od[2] = {};
  float mrun = -1e30f;
  float srun = 0.f;
  const float DTHR = 11.541560327111707f;  // 8 * log2(e)
  const int NT = N_ / 64;
  const int sw = (l31 & 7) << 4;           // byte-swizzle for LDS reads

  stageK(0, 0);
  stageV(0, 0);

  int cur = 0;
  for (int tile = 0; tile < NT; ++tile) {
    if (tile + 1 < NT) {
      stageK(cur ^ 1, (tile + 1) * 64);
      stageV(cur ^ 1, (tile + 1) * 64);
      WAITVM(4);            // current tile staged; next tile's 4 loads in flight
    } else {
      WAITVM(0);
    }
    __builtin_amdgcn_s_barrier();

    // ---- QK^T: S^T[key][q] per 32-key block ----
    f32x16 st[2];
    __builtin_amdgcn_s_setprio(1);
#pragma unroll
    for (int kb2 = 0; kb2 < 2; ++kb2) {
      f32x16 z = {};
#pragma unroll
      for (int f = 0; f < 4; ++f) {
        const int byt = (kb2 * 32 + l31) * 128 + ((f * 32 + hl * 16) ^ sw);
        const bf16x8 ka = *(const bf16x8*)&lK[cur][byt >> 1];
        z = __builtin_amdgcn_mfma_f32_32x32x16_bf16(ka, qf[f], z, 0, 0, 0);
      }
      st[kb2] = z;
    }
    __builtin_amdgcn_s_setprio(0);

    // ---- online softmax (log2 domain) with defer-max ----
    float mx = st[0][0];
#pragma unroll
    for (int r = 1; r < 16; ++r) mx = fmaxf(mx, st[0][r]);
#pragma unroll
    for (int r = 0; r < 16; ++r) mx = fmaxf(mx, st[1][r]);
    mx = fmaxf(mx, __shfl_xor(mx, 32));
    if (__any(mx > mrun + DTHR)) {
      const float mn = fmaxf(mrun, mx);
      const float sf = exp2f(mrun - mn);
      mrun = mn;
      srun *= sf;
#pragma unroll
      for (int dblk = 0; dblk < 2; ++dblk)
#pragma unroll
        for (int r = 0; r < 16; ++r) od[dblk][r] *= sf;
    }

    // ---- P = exp2(S - m), repack to PV B-fragments via permlane32_swap ----
    bf16x8 pb[4];
#pragma unroll
    for (int kb2 = 0; kb2 < 2; ++kb2) {
      float p[16];
#pragma unroll
      for (int r = 0; r < 16; ++r) {
        p[r] = exp2f(st[kb2][r] - mrun);
        srun += p[r];
      }
      unsigned qd[8];
#pragma unroll
      for (int i = 0; i < 8; ++i) qd[i] = pk2(p[2 * i], p[2 * i + 1]);
      pl32swap(qd[0], qd[2]);
      pl32swap(qd[1], qd[3]);
      pl32swap(qd[4], qd[6]);
      pl32swap(qd[5], qd[7]);
      union { unsigned u[4]; bf16x8 v; } f0, f1;
      f0.u[0] = qd[0];
      f0.u[1] = qd[1];
      f0.u[2] = qd[2];
      f0.u[3] = qd[3];
      f1.u[0] = qd[4];
      f1.u[1] = qd[5];
      f1.u[2] = qd[6];
      f1.u[3] = qd[7];
      pb[kb2 * 2 + 0] = f0.v;
      pb[kb2 * 2 + 1] = f1.v;
    }

    // ---- PV: O^T += V^T * P ----
    __builtin_amdgcn_s_setprio(1);
#pragma unroll
    for (int dblk = 0; dblk < 2; ++dblk) {
#pragma unroll
      for (int kf = 0; kf < 4; ++kf) {
        const int byt = (dblk * 32 + l31) * 128 + ((kf * 32 + hl * 16) ^ sw);
        const bf16x8 va = *(const bf16x8*)&lV[cur][byt >> 1];
        od[dblk] = __builtin_amdgcn_mfma_f32_32x32x16_bf16(va, pb[kf], od[dblk], 0, 0, 0);
      }
    }
    __builtin_amdgcn_s_setprio(0);

    WAITLGKM0;              // own LDS reads retired before buffer overwrite
    __builtin_amdgcn_s_barrier();
    cur ^= 1;
  }

  float s = srun + __shfl_xor(srun, 32);
  const float rinv = 1.0f / s;
  unsigned short* cp = ctx + ((size_t)(b * N_ + qb0 + l31)) * C_ + h * HD_;
#pragma unroll
  for (int dblk = 0; dblk < 2; ++dblk)
#pragma unroll
    for (int a = 0; a < 4; ++a) {
      const int r0 = a * 4;
      uint2 o;
      o.x = pk2(od[dblk][r0] * rinv, od[dblk][r0 + 1] * rinv);
      o.y = pk2(od[dblk][r0 + 2] * rinv, od[dblk][r0 + 3] * rinv);
      *(uint2*)(cp + dblk * 32 + a * 8 + hl * 4) = o;
    }
}

// ---------------- LayerNorm: x bf16 [BN, C] -> h bf16, wave-per-row ----------------
// 256 threads = 4 waves = 4 rows per block; pure shuffle reduce, no LDS/barriers.
__global__ __launch_bounds__(256)
void ln_kernel(const unsigned short* __restrict__ x, const float* __restrict__ lw,
               const float* __restrict__ lb, unsigned short* __restrict__ h) {
  const int w = threadIdx.x >> 6, lane = threadIdx.x & 63;
  const int row = blockIdx.x * 4 + w;
  const uint4* xr = (const uint4*)(x + (size_t)row * C_);  // 8 bf16 per uint4
  uint4 rv[2];
  float xv[16];
  float sum = 0.f;
#pragma unroll
  for (int i = 0; i < 2; ++i) {
    rv[i] = xr[lane + i * 64];
    const unsigned uu[4] = {rv[i].x, rv[i].y, rv[i].z, rv[i].w};
#pragma unroll
    for (int j = 0; j < 4; ++j) {
      xv[i * 8 + 2 * j]     = bf2f((unsigned short)(uu[j] & 0xffffu));
      xv[i * 8 + 2 * j + 1] = bf2f((unsigned short)(uu[j] >> 16));
      sum += xv[i * 8 + 2 * j] + xv[i * 8 + 2 * j + 1];
    }
  }
#pragma unroll
  for (int m = 1; m < 64; m <<= 1) sum += __shfl_xor(sum, m);
  const float mu = sum * (1.0f / C_);
  float sq = 0.f;
#pragma unroll
  for (int e = 0; e < 16; ++e) {
    const float d = xv[e] - mu;
    sq += d * d;
  }
#pragma unroll
  for (int m = 1; m < 64; m <<= 1) sq += __shfl_xor(sq, m);
  const float rstd = rsqrtf(sq * (1.0f / C_) + 1e-5f);
  uint4* ho = (uint4*)(h + (size_t)row * C_);
#pragma unroll
  for (int i = 0; i < 2; ++i) {
    const int e0 = (lane + i * 64) * 8;
    uint4 o;
    unsigned* op = (unsigned*)&o;
#pragma unroll
    for (int j = 0; j < 4; ++j) {
      const float a = (xv[i * 8 + 2 * j] - mu) * rstd * lw[e0 + 2 * j] + lb[e0 + 2 * j];
      const float bvl = (xv[i * 8 + 2 * j + 1] - mu) * rstd * lw[e0 + 2 * j + 1] + lb[e0 + 2 * j + 1];
      op[j] = pk2(a, bvl);
    }
    ho[lane + i * 64] = o;
  }
}

extern "C" void kernel_launch(void* const* d_in, const int* in_sizes, int n_in,
                              void* d_out, int out_size, void* d_ws, size_t ws_size,
                              hipStream_t stream) {
  const float* q   = (const float*)d_in[0];
  const float* k   = (const float*)d_in[1];
  const float* v   = (const float*)d_in[2];
  const float* Wq  = (const float*)d_in[3];
  const float* bq  = (const float*)d_in[4];
  const float* Wk  = (const float*)d_in[5];
  const float* bk  = (const float*)d_in[6];
  const float* Wv  = (const float*)d_in[7];
  const float* bv  = (const float*)d_in[8];
  const float* Wo  = (const float*)d_in[9];
  const float* bo  = (const float*)d_in[10];
  const float* lnw = (const float*)d_in[11];
  const float* lnb = (const float*)d_in[12];
  const float* W1  = (const float*)d_in[13];
  const float* b1  = (const float*)d_in[14];
  const float* W2  = (const float*)d_in[15];
  const float* b2  = (const float*)d_in[16];
  float* out = (float*)d_out;

  char* ws = (char*)d_ws;
  const size_t MB = 1024 * 1024;
  if (ws_size < 120 * MB) return;
  unsigned short* qb   = (unsigned short*)(ws + 0 * MB);
  unsigned short* kb   = (unsigned short*)(ws + 8 * MB);
  unsigned short* vb   = (unsigned short*)(ws + 16 * MB);
  unsigned short* Wqt  = (unsigned short*)(ws + 24 * MB);
  unsigned short* Wkt  = (unsigned short*)(ws + 26 * MB);
  unsigned short* Wvt  = (unsigned short*)(ws + 28 * MB);
  unsigned short* Wot  = (unsigned short*)(ws + 30 * MB);
  unsigned short* W1t  = (unsigned short*)(ws + 32 * MB);
  unsigned short* W2t  = (unsigned short*)(ws + 36 * MB);
  unsigned short* Qh   = (unsigned short*)(ws + 40 * MB);
  unsigned short* Kh   = (unsigned short*)(ws + 48 * MB);
  unsigned short* Vh   = (unsigned short*)(ws + 56 * MB);
  unsigned short* VhT  = (unsigned short*)(ws + 64 * MB);
  unsigned short* ctx  = (unsigned short*)(ws + 72 * MB);
  unsigned short* xfb  = (unsigned short*)(ws + 80 * MB);  // bf16 residual x (8 MB)
  unsigned short* hb   = (unsigned short*)(ws + 96 * MB);
  unsigned short* tbuf = (unsigned short*)(ws + 104 * MB);

  const int n8 = B_ * N_ * C_ / 8;
  cast3_bf16<<<dim3((n8 + 255) / 256, 1, 3), 256, 0, stream>>>(q, k, v, qb, kb, vb, n8);

  dim3 blk32(32, 8);
  wt_cast4<<<dim3(C_ / 32, C_ / 32, 4), blk32, 0, stream>>>(Wq, Wk, Wv, Wo, Wqt, Wkt, Wvt, Wot);
  wt_cast<<<dim3(FF_ / 32, C_ / 32), blk32, 0, stream>>>(W1, W1t, C_, FF_);
  wt_cast<<<dim3(C_ / 32, FF_ / 32), blk32, 0, stream>>>(W2, W2t, FF_, C_);

  gemm_qkv<<<dim3(B_ * N_ / 128, C_ / 128, 3), 256, 0, stream>>>(qb, kb, vb, Wqt, Wkt, Wvt,
                                                                 bq, bk, bv, Qh, Kh, Vh);

  vh_transpose<<<dim3(N_ / 32, HD_ / 32, B_ * H_), blk32, 0, stream>>>(Vh, VhT);
  attn_fwd<<<dim3((N_ / 128) * B_ * H_), 256, 0, stream>>>(Qh, Kh, VhT, ctx);

  gemm_n64<0><<<dim3(B_ * N_ / 128, C_ / 64), 256, 0, stream>>>(ctx, Wot, bo, q, nullptr, xfb,
                                                                B_ * N_, C_, C_);
  ln_kernel<<<dim3(B_ * N_ / 4), 256, 0, stream>>>(xfb, lnw, lnb, hb);
  gemm_bt<2><<<dim3(B_ * N_ / 128, FF_ / 128), 256, 0, stream>>>(hb, W1t, b1, nullptr, nullptr, tbuf,
                                                                 B_ * N_, FF_, C_);
  gemm_n64<1><<<dim3(B_ * N_ / 128, C_ / 64), 256, 0, stream>>>(tbuf, W2t, b2, xfb, out, nullptr,
                                                                B_ * N_, C_, FF_);
}

// Round 17
// 221.545 us; speedup vs baseline: 1.1276x; 1.0367x over previous
//
#include <hip/hip_runtime.h>

constexpr int B_ = 2, N_ = 2048, C_ = 1024, H_ = 16, HD_ = 64, FF_ = 2048;

typedef __attribute__((ext_vector_type(8))) __bf16 bf16x8;
typedef __attribute__((ext_vector_type(2))) __bf16 bf16x2;
typedef __attribute__((ext_vector_type(4))) float f32x4;
typedef __attribute__((ext_vector_type(16))) float f32x16;

#define WAITVM(n) asm volatile("s_waitcnt vmcnt(" #n ")" ::: "memory")
#define WAITLGKM0 asm volatile("s_waitcnt lgkmcnt(0)" ::: "memory")

__device__ __forceinline__ unsigned short f2bf(float f) {
  union { float f; unsigned int u; } v; v.f = f;
  unsigned int r = v.u + 0x7fffu + ((v.u >> 16) & 1u);
  return (unsigned short)(r >> 16);
}

__device__ __forceinline__ float bf2f(unsigned short u) {
  union { unsigned v; float f; } c;
  c.v = (unsigned)u << 16;
  return c.f;
}

__device__ __forceinline__ unsigned pk2(float a, float b) {
  bf16x2 p;
  p[0] = (__bf16)a;
  p[1] = (__bf16)b;
  union { bf16x2 v; unsigned u; } u;
  u.v = p;
  return u.u;
}

// v_permlane32_swap_b32 D,S:  newD = {D.lo, S.lo}, newS = {D.hi, S.hi}
__device__ __forceinline__ void pl32swap(unsigned& d, unsigned& s) {
  asm volatile("v_permlane32_swap_b32 %0, %1" : "+v"(d), "+v"(s));
}

__device__ __forceinline__ void gload_lds16(const unsigned short* g, unsigned short* l) {
  __builtin_amdgcn_global_load_lds((const __attribute__((address_space(1))) void*)g,
                                   (__attribute__((address_space(3))) void*)l, 16, 0, 0);
}

// XCD-chunk swizzle (attn only)
__device__ __forceinline__ int xcd_chunk(int bid, int nwg) {
  return (bid & 7) * (nwg >> 3) + (bid >> 3);
}

// ---------------- prep: all casts + weight transposes in ONE launch ----------------
// blocks [0,4096):    4 square CxC weight transposes (Wq,Wk,Wv,Wo), 1024 tiles each
// blocks [4096,6144): W1 (K=C, N=FF) transpose, 2048 tiles
// blocks [6144,8192): W2 (K=FF, N=C) transpose, 2048 tiles
// blocks [8192,14336): q/k/v f32->bf16 cast, 2048 blocks each
__global__ __launch_bounds__(256)
void prep(const float* __restrict__ q, const float* __restrict__ k, const float* __restrict__ v,
          const float* __restrict__ Wq, const float* __restrict__ Wk,
          const float* __restrict__ Wv, const float* __restrict__ Wo,
          const float* __restrict__ W1, const float* __restrict__ W2,
          unsigned short* __restrict__ qb, unsigned short* __restrict__ kb,
          unsigned short* __restrict__ vb, unsigned short* __restrict__ Wqt,
          unsigned short* __restrict__ Wkt, unsigned short* __restrict__ Wvt,
          unsigned short* __restrict__ Wot, unsigned short* __restrict__ W1t,
          unsigned short* __restrict__ W2t) {
  __shared__ unsigned short tile[32][33];
  const int id = blockIdx.x;
  const int t = threadIdx.x;

  if (id >= 8192) {
    // ---- cast region ----
    const int cid = id - 8192;
    const int z = cid >> 11;              // 2048 blocks per tensor
    const int i = (cid & 2047) * 256 + t;
    const float* in = z == 0 ? q : (z == 1 ? k : v);
    unsigned short* out = z == 0 ? qb : (z == 1 ? kb : vb);
    const float4 a = ((const float4*)in)[2 * i];
    const float4 b = ((const float4*)in)[2 * i + 1];
    uint4 o;
    o.x = (unsigned)f2bf(a.x) | ((unsigned)f2bf(a.y) << 16);
    o.y = (unsigned)f2bf(a.z) | ((unsigned)f2bf(a.w) << 16);
    o.z = (unsigned)f2bf(b.x) | ((unsigned)f2bf(b.y) << 16);
    o.w = (unsigned)f2bf(b.z) | ((unsigned)f2bf(b.w) << 16);
    ((uint4*)out)[i] = o;
    return;
  }

  // ---- weight transpose region: W[K][N] f32 -> Wt[N][K] bf16 ----
  const float* W;
  unsigned short* Wt;
  int K, Nn, n0, k0;
  if (id < 4096) {
    const int wsel = id >> 10, tl = id & 1023;
    W = wsel == 0 ? Wq : (wsel == 1 ? Wk : (wsel == 2 ? Wv : Wo));
    Wt = wsel == 0 ? Wqt : (wsel == 1 ? Wkt : (wsel == 2 ? Wvt : Wot));
    K = C_; Nn = C_;
    n0 = (tl & 31) * 32; k0 = (tl >> 5) * 32;
  } else if (id < 6144) {
    const int tl = id - 4096;
    W = W1; Wt = W1t; K = C_; Nn = FF_;
    n0 = (tl & 63) * 32; k0 = (tl >> 6) * 32;
  } else {
    const int tl = id - 6144;
    W = W2; Wt = W2t; K = FF_; Nn = C_;
    n0 = (tl & 31) * 32; k0 = (tl >> 5) * 32;
  }
  const int tx = t & 31, ty = t >> 5;
#pragma unroll
  for (int r = 0; r < 4; ++r)
    tile[ty + r * 8][tx] = f2bf(W[(size_t)(k0 + ty + r * 8) * Nn + n0 + tx]);
  __syncthreads();
#pragma unroll
  for (int r = 0; r < 4; ++r)
    Wt[(size_t)(n0 + ty + r * 8) * K + k0 + tx] = tile[tx][ty + r * 8];
}

// ---------------- 128x128 GEMM (2-phase dbuf), z-fused QKV ----------------
// z==0 (Q): out bf16 pre-scaled by c1 = 1/sqrt(HD)*log2(e).
// z==1 (K): out bf16 [B,N,C].
// z==2 (V): out written TRANSPOSED directly to VhT [B*H][HD][N] (fused vh_transpose).
__global__ __launch_bounds__(256, 2)
void gemm_qkv(const unsigned short* __restrict__ A0, const unsigned short* __restrict__ A1,
              const unsigned short* __restrict__ A2, const unsigned short* __restrict__ B0,
              const unsigned short* __restrict__ B1, const unsigned short* __restrict__ B2,
              const float* __restrict__ c0, const float* __restrict__ c1v,
              const float* __restrict__ c2, unsigned short* __restrict__ O0,
              unsigned short* __restrict__ O1, unsigned short* __restrict__ O2) {
  const int z = blockIdx.z;
  const unsigned short* A = z == 0 ? A0 : (z == 1 ? A1 : A2);
  const unsigned short* Bt = z == 0 ? B0 : (z == 1 ? B1 : B2);
  const float* bias = z == 0 ? c0 : (z == 1 ? c1v : c2);
  const float sc = z == 0 ? 0.18033688011112042f : 1.0f;
  const int K = C_, Nn = C_;

  __shared__ unsigned short lA[2][128 * 64];
  __shared__ unsigned short lB[2][128 * 64];
  const int t = threadIdx.x;
  const int lane = t & 63;
  const int w = t >> 6;
  const int wm = w >> 1, wn = w & 1;
  const int l15 = lane & 15, g = lane >> 4;

  const unsigned short* Ab = A + (size_t)blockIdx.x * 128 * K;
  const unsigned short* Bb = Bt + (size_t)blockIdx.y * 128 * K;

  auto stage = [&](int buf, int k0) {
#pragma unroll
    for (int i = 0; i < 4; ++i) {
      int id = i * 256 + t;
      gload_lds16(Ab + (size_t)(id >> 3) * K + k0 + (id & 7) * 8, &lA[buf][id * 8]);
    }
#pragma unroll
    for (int i = 0; i < 4; ++i) {
      int id = i * 256 + t;
      gload_lds16(Bb + (size_t)(id >> 3) * K + k0 + (id & 7) * 8, &lB[buf][id * 8]);
    }
  };

  f32x4 acc[4][4] = {};

  stage(0, 0);
  __syncthreads();
  int cur = 0;
  for (int k0 = 0; k0 < K; k0 += 64) {
    if (k0 + 64 < K) stage(cur ^ 1, k0 + 64);
#pragma unroll
    for (int kk = 0; kk < 2; ++kk) {
      bf16x8 af[4], bfr[4];
#pragma unroll
      for (int mi = 0; mi < 4; ++mi)
        af[mi] = *(const bf16x8*)&lA[cur][(wm * 64 + mi * 16 + l15) * 64 + kk * 32 + g * 8];
#pragma unroll
      for (int ni = 0; ni < 4; ++ni)
        bfr[ni] = *(const bf16x8*)&lB[cur][(wn * 64 + ni * 16 + l15) * 64 + kk * 32 + g * 8];
      __builtin_amdgcn_s_setprio(1);
#pragma unroll
      for (int mi = 0; mi < 4; ++mi)
#pragma unroll
        for (int ni = 0; ni < 4; ++ni)
          acc[mi][ni] = __builtin_amdgcn_mfma_f32_16x16x32_bf16(af[mi], bfr[ni], acc[mi][ni], 0, 0, 0);
      __builtin_amdgcn_s_setprio(0);
    }
    __syncthreads();
    cur ^= 1;
  }

#pragma unroll
  for (int mi = 0; mi < 4; ++mi)
#pragma unroll
    for (int ni = 0; ni < 4; ++ni) {
      const int col = blockIdx.y * 128 + wn * 64 + ni * 16 + l15;
      const float bcol = bias[col];
      if (z == 2) {
        // fused transpose write: VhT[((b*H + h)*HD + d)][n], 4 consecutive n
        const int hh = col >> 6, d = col & 63;
        const int row0 = blockIdx.x * 128 + wm * 64 + mi * 16 + g * 4;
        const int bb = row0 >> 11, nn = row0 & (N_ - 1);
        uint2 o;
        o.x = pk2(acc[mi][ni][0] + bcol, acc[mi][ni][1] + bcol);
        o.y = pk2(acc[mi][ni][2] + bcol, acc[mi][ni][3] + bcol);
        *(uint2*)(O2 + ((size_t)((bb * H_ + hh) * HD_ + d)) * N_ + nn) = o;
      } else {
        unsigned short* outB = z == 0 ? O0 : O1;
#pragma unroll
        for (int r = 0; r < 4; ++r) {
          const int row = blockIdx.x * 128 + wm * 64 + mi * 16 + g * 4 + r;
          outB[(size_t)row * Nn + col] = f2bf((acc[mi][ni][r] + bcol) * sc);
        }
      }
    }
}

// ---------------- 128x128 GEMM (2-phase dbuf) with epilogues ----------------
template <int EPI>
__global__ __launch_bounds__(256, 2)
void gemm_bt(const unsigned short* __restrict__ A, const unsigned short* __restrict__ Bt,
             const float* __restrict__ bias, const float* __restrict__ resid,
             float* __restrict__ outF, unsigned short* __restrict__ outB,
             int M, int N, int K) {
  __shared__ unsigned short lA[2][128 * 64];
  __shared__ unsigned short lB[2][128 * 64];
  const int t = threadIdx.x;
  const int lane = t & 63;
  const int w = t >> 6;
  const int wm = w >> 1, wn = w & 1;
  const int l15 = lane & 15, g = lane >> 4;

  const unsigned short* Ab = A + (size_t)blockIdx.x * 128 * K;
  const unsigned short* Bb = Bt + (size_t)blockIdx.y * 128 * K;

  auto stage = [&](int buf, int k0) {
#pragma unroll
    for (int i = 0; i < 4; ++i) {
      int id = i * 256 + t;
      gload_lds16(Ab + (size_t)(id >> 3) * K + k0 + (id & 7) * 8, &lA[buf][id * 8]);
    }
#pragma unroll
    for (int i = 0; i < 4; ++i) {
      int id = i * 256 + t;
      gload_lds16(Bb + (size_t)(id >> 3) * K + k0 + (id & 7) * 8, &lB[buf][id * 8]);
    }
  };

  f32x4 acc[4][4] = {};

  stage(0, 0);
  __syncthreads();
  int cur = 0;
  for (int k0 = 0; k0 < K; k0 += 64) {
    if (k0 + 64 < K) stage(cur ^ 1, k0 + 64);
#pragma unroll
    for (int kk = 0; kk < 2; ++kk) {
      bf16x8 af[4], bfr[4];
#pragma unroll
      for (int mi = 0; mi < 4; ++mi)
        af[mi] = *(const bf16x8*)&lA[cur][(wm * 64 + mi * 16 + l15) * 64 + kk * 32 + g * 8];
#pragma unroll
      for (int ni = 0; ni < 4; ++ni)
        bfr[ni] = *(const bf16x8*)&lB[cur][(wn * 64 + ni * 16 + l15) * 64 + kk * 32 + g * 8];
      __builtin_amdgcn_s_setprio(1);
#pragma unroll
      for (int mi = 0; mi < 4; ++mi)
#pragma unroll
        for (int ni = 0; ni < 4; ++ni)
          acc[mi][ni] = __builtin_amdgcn_mfma_f32_16x16x32_bf16(af[mi], bfr[ni], acc[mi][ni], 0, 0, 0);
      __builtin_amdgcn_s_setprio(0);
    }
    __syncthreads();
    cur ^= 1;
  }

#pragma unroll
  for (int mi = 0; mi < 4; ++mi)
#pragma unroll
    for (int ni = 0; ni < 4; ++ni) {
      const int col = blockIdx.y * 128 + wn * 64 + ni * 16 + l15;
      const float bcol = bias[col];
#pragma unroll
      for (int r = 0; r < 4; ++r) {
        const int row = blockIdx.x * 128 + wm * 64 + mi * 16 + g * 4 + r;
        const size_t o = (size_t)row * N + col;
        float val = acc[mi][ni][r] + bcol;
        if (EPI == 0) {
          outB[o] = f2bf(val);
        } else if (EPI == 1) {
          outF[o] = val + resid[o];
        } else {
          float ge = 0.5f * val * (1.0f + erff(val * 0.70710678118654752f));
          outB[o] = f2bf(ge);
        }
      }
    }
}

// ---------------- 128x64-tile GEMM (2-phase dbuf; skinny N) ----------------
// MODE 0: resid f32 (q), out bf16 = val + bias + resid   (o-proj -> xfb)
// MODE 1: resid bf16 (xfb), out f32 = val + bias + resid (ffn-down -> d_out)
template <int MODE>
__global__ __launch_bounds__(256, 2)
void gemm_n64(const unsigned short* __restrict__ A, const unsigned short* __restrict__ Bt,
              const float* __restrict__ bias, const void* __restrict__ residv,
              float* __restrict__ outF, unsigned short* __restrict__ outB,
              int M, int N, int K) {
  __shared__ unsigned short lA[2][128 * 64];
  __shared__ unsigned short lB[2][64 * 64];
  const int t = threadIdx.x;
  const int lane = t & 63;
  const int w = t >> 6;
  const int wm = w >> 1, wn = w & 1;
  const int l15 = lane & 15, g = lane >> 4;

  const unsigned short* Ab = A + (size_t)blockIdx.x * 128 * K;
  const unsigned short* Bb = Bt + (size_t)blockIdx.y * 64 * K;

  auto stage = [&](int buf, int k0) {
#pragma unroll
    for (int i = 0; i < 4; ++i) {
      int id = i * 256 + t;
      gload_lds16(Ab + (size_t)(id >> 3) * K + k0 + (id & 7) * 8, &lA[buf][id * 8]);
    }
#pragma unroll
    for (int i = 0; i < 2; ++i) {
      int id = i * 256 + t;
      gload_lds16(Bb + (size_t)(id >> 3) * K + k0 + (id & 7) * 8, &lB[buf][id * 8]);
    }
  };

  f32x4 acc[4][2] = {};

  stage(0, 0);
  __syncthreads();
  int cur = 0;
  for (int k0 = 0; k0 < K; k0 += 64) {
    if (k0 + 64 < K) stage(cur ^ 1, k0 + 64);
#pragma unroll
    for (int kk = 0; kk < 2; ++kk) {
      bf16x8 af[4], bfr[2];
#pragma unroll
      for (int mi = 0; mi < 4; ++mi)
        af[mi] = *(const bf16x8*)&lA[cur][(wm * 64 + mi * 16 + l15) * 64 + kk * 32 + g * 8];
#pragma unroll
      for (int ni = 0; ni < 2; ++ni)
        bfr[ni] = *(const bf16x8*)&lB[cur][(wn * 32 + ni * 16 + l15) * 64 + kk * 32 + g * 8];
      __builtin_amdgcn_s_setprio(1);
#pragma unroll
      for (int mi = 0; mi < 4; ++mi)
#pragma unroll
        for (int ni = 0; ni < 2; ++ni)
          acc[mi][ni] = __builtin_amdgcn_mfma_f32_16x16x32_bf16(af[mi], bfr[ni], acc[mi][ni], 0, 0, 0);
      __builtin_amdgcn_s_setprio(0);
    }
    __syncthreads();
    cur ^= 1;
  }

#pragma unroll
  for (int mi = 0; mi < 4; ++mi)
#pragma unroll
    for (int ni = 0; ni < 2; ++ni) {
      const int col = blockIdx.y * 64 + wn * 32 + ni * 16 + l15;
      const float bcol = bias[col];
#pragma unroll
      for (int r = 0; r < 4; ++r) {
        const int row = blockIdx.x * 128 + wm * 64 + mi * 16 + g * 4 + r;
        const size_t o = (size_t)row * N + col;
        const float val = acc[mi][ni][r] + bcol;
        if (MODE == 0) {
          const float* resid = (const float*)residv;
          outB[o] = f2bf(val + resid[o]);
        } else {
          const unsigned short* resid = (const unsigned short*)residv;
          outF[o] = val + bf2f(resid[o]);
        }
      }
    }
}

// ---------------- flash attention (r13-best: 32x32 MFMA + permlane32_swap) ----------------
// 512 blocks (XCD-chunk swizzled), 256 threads = 4 waves, 32 q-rows per wave.
// QK^T: S^T = mfma_32x32x16(K_frag, Q_frag); P repack via v_permlane32_swap;
// PV: mfma_32x32x16(V^T, P). K/V LDS XOR-swizzled, counted vmcnt.
// Q pre-scaled by c1 -> S in log2 units.
__global__ __launch_bounds__(256, 2)
void attn_fwd(const unsigned short* __restrict__ Qh, const unsigned short* __restrict__ Kh,
              const unsigned short* __restrict__ VhT, unsigned short* __restrict__ ctx) {
  __shared__ unsigned short lK[2][64 * 64];
  __shared__ unsigned short lV[2][64 * 64];

  const int t = threadIdx.x, lane = t & 63, w = t >> 6;
  const int l31 = lane & 31, hl = lane >> 5;
  const int swz = xcd_chunk(blockIdx.x, (N_ / 128) * B_ * H_);
  const int bx = swz & (N_ / 128 - 1), bh = swz >> 4;
  const int b = bh >> 4, h = bh & 15;
  const int qb0 = bx * 128 + w * 32;

  const unsigned short* Qb = Qh + (size_t)b * N_ * C_ + h * HD_;
  const unsigned short* Kb = Kh + (size_t)b * N_ * C_ + h * HD_;
  const unsigned short* Vb = VhT + (size_t)bh * HD_ * N_;

  // Q frags (B-operand): lane holds Q[q = qb0+l31][d = f*16 + hl*8 + j]
  bf16x8 qf[4];
#pragma unroll
  for (int f = 0; f < 4; ++f)
    qf[f] = *(const bf16x8*)(Qb + (size_t)(qb0 + l31) * C_ + f * 16 + hl * 8);

  // stage: linear LDS dest, inverse-swizzled global source (rule #21)
  auto stageK = [&](int buf, int kb) {
#pragma unroll
    for (int i = 0; i < 2; ++i) {
      int o = (i * 256 + t) * 16;                 // tile byte offset
      int r = o >> 7;                             // row (key)
      int c = (o & 127) ^ ((r & 7) << 4);         // swizzled byte col
      gload_lds16(Kb + (size_t)(kb + r) * C_ + (c >> 1), &lK[buf][o >> 1]);
    }
  };
  auto stageV = [&](int buf, int kb) {
#pragma unroll
    for (int i = 0; i < 2; ++i) {
      int o = (i * 256 + t) * 16;
      int r = o >> 7;                             // row (d)
      int c = (o & 127) ^ ((r & 7) << 4);
      gload_lds16(Vb + (size_t)r * N_ + kb + (c >> 1), &lV[buf][o >> 1]);
    }
  };

  f32x16 od[2] = {};
  float mrun = -1e30f;
  float srun = 0.f;
  const float DTHR = 11.541560327111707f;  // 8 * log2(e)
  const int NT = N_ / 64;
  const int sw = (l31 & 7) << 4;           // byte-swizzle for LDS reads

  stageK(0, 0);
  stageV(0, 0);

  int cur = 0;
  for (int tile = 0; tile < NT; ++tile) {
    if (tile + 1 < NT) {
      stageK(cur ^ 1, (tile + 1) * 64);
      stageV(cur ^ 1, (tile + 1) * 64);
      WAITVM(4);            // current tile staged; next tile's 4 loads in flight
    } else {
      WAITVM(0);
    }
    __builtin_amdgcn_s_barrier();

    // ---- QK^T: S^T[key][q] per 32-key block ----
    f32x16 st[2];
    __builtin_amdgcn_s_setprio(1);
#pragma unroll
    for (int kb2 = 0; kb2 < 2; ++kb2) {
      f32x16 z = {};
#pragma unroll
      for (int f = 0; f < 4; ++f) {
        const int byt = (kb2 * 32 + l31) * 128 + ((f * 32 + hl * 16) ^ sw);
        const bf16x8 ka = *(const bf16x8*)&lK[cur][byt >> 1];
        z = __builtin_amdgcn_mfma_f32_32x32x16_bf16(ka, qf[f], z, 0, 0, 0);
      }
      st[kb2] = z;
    }
    __builtin_amdgcn_s_setprio(0);

    // ---- online softmax (log2 domain) with defer-max ----
    float mx = st[0][0];
#pragma unroll
    for (int r = 1; r < 16; ++r) mx = fmaxf(mx, st[0][r]);
#pragma unroll
    for (int r = 0; r < 16; ++r) mx = fmaxf(mx, st[1][r]);
    mx = fmaxf(mx, __shfl_xor(mx, 32));
    if (__any(mx > mrun + DTHR)) {
      const float mn = fmaxf(mrun, mx);
      const float sf = exp2f(mrun - mn);
      mrun = mn;
      srun *= sf;
#pragma unroll
      for (int dblk = 0; dblk < 2; ++dblk)
#pragma unroll
        for (int r = 0; r < 16; ++r) od[dblk][r] *= sf;
    }

    // ---- P = exp2(S - m), repack to PV B-fragments via permlane32_swap ----
    bf16x8 pb[4];
#pragma unroll
    for (int kb2 = 0; kb2 < 2; ++kb2) {
      float p[16];
#pragma unroll
      for (int r = 0; r < 16; ++r) {
        p[r] = exp2f(st[kb2][r] - mrun);
        srun += p[r];
      }
      unsigned qd[8];
#pragma unroll
      for (int i = 0; i < 8; ++i) qd[i] = pk2(p[2 * i], p[2 * i + 1]);
      pl32swap(qd[0], qd[2]);
      pl32swap(qd[1], qd[3]);
      pl32swap(qd[4], qd[6]);
      pl32swap(qd[5], qd[7]);
      union { unsigned u[4]; bf16x8 v; } f0, f1;
      f0.u[0] = qd[0];
      f0.u[1] = qd[1];
      f0.u[2] = qd[2];
      f0.u[3] = qd[3];
      f1.u[0] = qd[4];
      f1.u[1] = qd[5];
      f1.u[2] = qd[6];
      f1.u[3] = qd[7];
      pb[kb2 * 2 + 0] = f0.v;
      pb[kb2 * 2 + 1] = f1.v;
    }

    // ---- PV: O^T += V^T * P ----
    __builtin_amdgcn_s_setprio(1);
#pragma unroll
    for (int dblk = 0; dblk < 2; ++dblk) {
#pragma unroll
      for (int kf = 0; kf < 4; ++kf) {
        const int byt = (dblk * 32 + l31) * 128 + ((kf * 32 + hl * 16) ^ sw);
        const bf16x8 va = *(const bf16x8*)&lV[cur][byt >> 1];
        od[dblk] = __builtin_amdgcn_mfma_f32_32x32x16_bf16(va, pb[kf], od[dblk], 0, 0, 0);
      }
    }
    __builtin_amdgcn_s_setprio(0);

    WAITLGKM0;              // own LDS reads retired before buffer overwrite
    __builtin_amdgcn_s_barrier();
    cur ^= 1;
  }

  float s = srun + __shfl_xor(srun, 32);
  const float rinv = 1.0f / s;
  unsigned short* cp = ctx + ((size_t)(b * N_ + qb0 + l31)) * C_ + h * HD_;
#pragma unroll
  for (int dblk = 0; dblk < 2; ++dblk)
#pragma unroll
    for (int a = 0; a < 4; ++a) {
      const int r0 = a * 4;
      uint2 o;
      o.x = pk2(od[dblk][r0] * rinv, od[dblk][r0 + 1] * rinv);
      o.y = pk2(od[dblk][r0 + 2] * rinv, od[dblk][r0 + 3] * rinv);
      *(uint2*)(cp + dblk * 32 + a * 8 + hl * 4) = o;
    }
}

// ---------------- LayerNorm: x bf16 [BN, C] -> h bf16, wave-per-row ----------------
__global__ __launch_bounds__(256)
void ln_kernel(const unsigned short* __restrict__ x, const float* __restrict__ lw,
               const float* __restrict__ lb, unsigned short* __restrict__ h) {
  const int w = threadIdx.x >> 6, lane = threadIdx.x & 63;
  const int row = blockIdx.x * 4 + w;
  const uint4* xr = (const uint4*)(x + (size_t)row * C_);  // 8 bf16 per uint4
  uint4 rv[2];
  float xv[16];
  float sum = 0.f;
#pragma unroll
  for (int i = 0; i < 2; ++i) {
    rv[i] = xr[lane + i * 64];
    const unsigned uu[4] = {rv[i].x, rv[i].y, rv[i].z, rv[i].w};
#pragma unroll
    for (int j = 0; j < 4; ++j) {
      xv[i * 8 + 2 * j]     = bf2f((unsigned short)(uu[j] & 0xffffu));
      xv[i * 8 + 2 * j + 1] = bf2f((unsigned short)(uu[j] >> 16));
      sum += xv[i * 8 + 2 * j] + xv[i * 8 + 2 * j + 1];
    }
  }
#pragma unroll
  for (int m = 1; m < 64; m <<= 1) sum += __shfl_xor(sum, m);
  const float mu = sum * (1.0f / C_);
  float sq = 0.f;
#pragma unroll
  for (int e = 0; e < 16; ++e) {
    const float d = xv[e] - mu;
    sq += d * d;
  }
#pragma unroll
  for (int m = 1; m < 64; m <<= 1) sq += __shfl_xor(sq, m);
  const float rstd = rsqrtf(sq * (1.0f / C_) + 1e-5f);
  uint4* ho = (uint4*)(h + (size_t)row * C_);
#pragma unroll
  for (int i = 0; i < 2; ++i) {
    const int e0 = (lane + i * 64) * 8;
    uint4 o;
    unsigned* op = (unsigned*)&o;
#pragma unroll
    for (int j = 0; j < 4; ++j) {
      const float a = (xv[i * 8 + 2 * j] - mu) * rstd * lw[e0 + 2 * j] + lb[e0 + 2 * j];
      const float bvl = (xv[i * 8 + 2 * j + 1] - mu) * rstd * lw[e0 + 2 * j + 1] + lb[e0 + 2 * j + 1];
      op[j] = pk2(a, bvl);
    }
    ho[lane + i * 64] = o;
  }
}

extern "C" void kernel_launch(void* const* d_in, const int* in_sizes, int n_in,
                              void* d_out, int out_size, void* d_ws, size_t ws_size,
                              hipStream_t stream) {
  const float* q   = (const float*)d_in[0];
  const float* k   = (const float*)d_in[1];
  const float* v   = (const float*)d_in[2];
  const float* Wq  = (const float*)d_in[3];
  const float* bq  = (const float*)d_in[4];
  const float* Wk  = (const float*)d_in[5];
  const float* bk  = (const float*)d_in[6];
  const float* Wv  = (const float*)d_in[7];
  const float* bv  = (const float*)d_in[8];
  const float* Wo  = (const float*)d_in[9];
  const float* bo  = (const float*)d_in[10];
  const float* lnw = (const float*)d_in[11];
  const float* lnb = (const float*)d_in[12];
  const float* W1  = (const float*)d_in[13];
  const float* b1  = (const float*)d_in[14];
  const float* W2  = (const float*)d_in[15];
  const float* b2  = (const float*)d_in[16];
  float* out = (float*)d_out;

  char* ws = (char*)d_ws;
  const size_t MB = 1024 * 1024;
  if (ws_size < 120 * MB) return;
  unsigned short* qb   = (unsigned short*)(ws + 0 * MB);
  unsigned short* kb   = (unsigned short*)(ws + 8 * MB);
  unsigned short* vb   = (unsigned short*)(ws + 16 * MB);
  unsigned short* Wqt  = (unsigned short*)(ws + 24 * MB);
  unsigned short* Wkt  = (unsigned short*)(ws + 26 * MB);
  unsigned short* Wvt  = (unsigned short*)(ws + 28 * MB);
  unsigned short* Wot  = (unsigned short*)(ws + 30 * MB);
  unsigned short* W1t  = (unsigned short*)(ws + 32 * MB);
  unsigned short* W2t  = (unsigned short*)(ws + 36 * MB);
  unsigned short* Qh   = (unsigned short*)(ws + 40 * MB);
  unsigned short* Kh   = (unsigned short*)(ws + 48 * MB);
  unsigned short* VhT  = (unsigned short*)(ws + 64 * MB);
  unsigned short* ctx  = (unsigned short*)(ws + 72 * MB);
  unsigned short* xfb  = (unsigned short*)(ws + 80 * MB);  // bf16 residual x (8 MB)
  unsigned short* hb   = (unsigned short*)(ws + 96 * MB);
  unsigned short* tbuf = (unsigned short*)(ws + 104 * MB);

  prep<<<dim3(14336), 256, 0, stream>>>(q, k, v, Wq, Wk, Wv, Wo, W1, W2,
                                        qb, kb, vb, Wqt, Wkt, Wvt, Wot, W1t, W2t);

  gemm_qkv<<<dim3(B_ * N_ / 128, C_ / 128, 3), 256, 0, stream>>>(qb, kb, vb, Wqt, Wkt, Wvt,
                                                                 bq, bk, bv, Qh, Kh, VhT);

  attn_fwd<<<dim3((N_ / 128) * B_ * H_), 256, 0, stream>>>(Qh, Kh, VhT, ctx);

  gemm_n64<0><<<dim3(B_ * N_ / 128, C_ / 64), 256, 0, stream>>>(ctx, Wot, bo, q, nullptr, xfb,
                                                                B_ * N_, C_, C_);
  ln_kernel<<<dim3(B_ * N_ / 4), 256, 0, stream>>>(xfb, lnw, lnb, hb);
  gemm_bt<2><<<dim3(B_ * N_ / 128, FF_ / 128), 256, 0, stream>>>(hb, W1t, b1, nullptr, nullptr, tbuf,
                                                                 B_ * N_, FF_, C_);
  gemm_n64<1><<<dim3(B_ * N_ / 128, C_ / 64), 256, 0, stream>>>(tbuf, W2t, b2, xfb, out, nullptr,
                                                                B_ * N_, C_, FF_);
}

// Round 18
// 216.410 us; speedup vs baseline: 1.1543x; 1.0237x over previous
//
#include <hip/hip_runtime.h>

constexpr int B_ = 2, N_ = 2048, C_ = 1024, H_ = 16, HD_ = 64, FF_ = 2048;

typedef __attribute__((ext_vector_type(8))) __bf16 bf16x8;
typedef __attribute__((ext_vector_type(2))) __bf16 bf16x2;
typedef __attribute__((ext_vector_type(4))) float f32x4;
typedef __attribute__((ext_vector_type(16))) float f32x16;

#define WAITVM(n) asm volatile("s_waitcnt vmcnt(" #n ")" ::: "memory")
#define WAITLGKM0 asm volatile("s_waitcnt lgkmcnt(0)" ::: "memory")

__device__ __forceinline__ unsigned short f2bf(float f) {
  union { float f; unsigned int u; } v; v.f = f;
  unsigned int r = v.u + 0x7fffu + ((v.u >> 16) & 1u);
  return (unsigned short)(r >> 16);
}

__device__ __forceinline__ float bf2f(unsigned short u) {
  union { unsigned v; float f; } c;
  c.v = (unsigned)u << 16;
  return c.f;
}

__device__ __forceinline__ unsigned pk2(float a, float b) {
  bf16x2 p;
  p[0] = (__bf16)a;
  p[1] = (__bf16)b;
  union { bf16x2 v; unsigned u; } u;
  u.v = p;
  return u.u;
}

// v_permlane32_swap_b32 D,S:  newD = {D.lo, S.lo}, newS = {D.hi, S.hi}
__device__ __forceinline__ void pl32swap(unsigned& d, unsigned& s) {
  asm volatile("v_permlane32_swap_b32 %0, %1" : "+v"(d), "+v"(s));
}

__device__ __forceinline__ void gload_lds16(const unsigned short* g, unsigned short* l) {
  __builtin_amdgcn_global_load_lds((const __attribute__((address_space(1))) void*)g,
                                   (__attribute__((address_space(3))) void*)l, 16, 0, 0);
}

// XCD-chunk swizzle (attn only)
__device__ __forceinline__ int xcd_chunk(int bid, int nwg) {
  return (bid & 7) * (nwg >> 3) + (bid >> 3);
}

// ---------------- prep: all casts + weight transposes in ONE launch ----------------
__global__ __launch_bounds__(256)
void prep(const float* __restrict__ q, const float* __restrict__ k, const float* __restrict__ v,
          const float* __restrict__ Wq, const float* __restrict__ Wk,
          const float* __restrict__ Wv, const float* __restrict__ Wo,
          const float* __restrict__ W1, const float* __restrict__ W2,
          unsigned short* __restrict__ qb, unsigned short* __restrict__ kb,
          unsigned short* __restrict__ vb, unsigned short* __restrict__ Wqt,
          unsigned short* __restrict__ Wkt, unsigned short* __restrict__ Wvt,
          unsigned short* __restrict__ Wot, unsigned short* __restrict__ W1t,
          unsigned short* __restrict__ W2t) {
  __shared__ unsigned short tile[32][33];
  const int id = blockIdx.x;
  const int t = threadIdx.x;

  if (id >= 8192) {
    const int cid = id - 8192;
    const int z = cid >> 11;
    const int i = (cid & 2047) * 256 + t;
    const float* in = z == 0 ? q : (z == 1 ? k : v);
    unsigned short* out = z == 0 ? qb : (z == 1 ? kb : vb);
    const float4 a = ((const float4*)in)[2 * i];
    const float4 b = ((const float4*)in)[2 * i + 1];
    uint4 o;
    o.x = (unsigned)f2bf(a.x) | ((unsigned)f2bf(a.y) << 16);
    o.y = (unsigned)f2bf(a.z) | ((unsigned)f2bf(a.w) << 16);
    o.z = (unsigned)f2bf(b.x) | ((unsigned)f2bf(b.y) << 16);
    o.w = (unsigned)f2bf(b.z) | ((unsigned)f2bf(b.w) << 16);
    ((uint4*)out)[i] = o;
    return;
  }

  const float* W;
  unsigned short* Wt;
  int K, Nn, n0, k0;
  if (id < 4096) {
    const int wsel = id >> 10, tl = id & 1023;
    W = wsel == 0 ? Wq : (wsel == 1 ? Wk : (wsel == 2 ? Wv : Wo));
    Wt = wsel == 0 ? Wqt : (wsel == 1 ? Wkt : (wsel == 2 ? Wvt : Wot));
    K = C_; Nn = C_;
    n0 = (tl & 31) * 32; k0 = (tl >> 5) * 32;
  } else if (id < 6144) {
    const int tl = id - 4096;
    W = W1; Wt = W1t; K = C_; Nn = FF_;
    n0 = (tl & 63) * 32; k0 = (tl >> 6) * 32;
  } else {
    const int tl = id - 6144;
    W = W2; Wt = W2t; K = FF_; Nn = C_;
    n0 = (tl & 31) * 32; k0 = (tl >> 5) * 32;
  }
  const int tx = t & 31, ty = t >> 5;
#pragma unroll
  for (int r = 0; r < 4; ++r)
    tile[ty + r * 8][tx] = f2bf(W[(size_t)(k0 + ty + r * 8) * Nn + n0 + tx]);
  __syncthreads();
#pragma unroll
  for (int r = 0; r < 4; ++r)
    Wt[(size_t)(n0 + ty + r * 8) * K + k0 + tx] = tile[tx][ty + r * 8];
}

// ---------------- 128x128 GEMM (single-buffer, 3 blocks/CU), z-fused QKV ----------------
// z==0 (Q): out bf16 pre-scaled by c1. z==1 (K): out bf16. z==2 (V): transposed -> VhT.
__global__ __launch_bounds__(256, 3)
void gemm_qkv(const unsigned short* __restrict__ A0, const unsigned short* __restrict__ A1,
              const unsigned short* __restrict__ A2, const unsigned short* __restrict__ B0,
              const unsigned short* __restrict__ B1, const unsigned short* __restrict__ B2,
              const float* __restrict__ c0, const float* __restrict__ c1v,
              const float* __restrict__ c2, unsigned short* __restrict__ O0,
              unsigned short* __restrict__ O1, unsigned short* __restrict__ O2) {
  const int z = blockIdx.z;
  const unsigned short* A = z == 0 ? A0 : (z == 1 ? A1 : A2);
  const unsigned short* Bt = z == 0 ? B0 : (z == 1 ? B1 : B2);
  const float* bias = z == 0 ? c0 : (z == 1 ? c1v : c2);
  const float sc = z == 0 ? 0.18033688011112042f : 1.0f;
  const int K = C_, Nn = C_;

  __shared__ unsigned short lA[128 * 64];
  __shared__ unsigned short lB[128 * 64];
  const int t = threadIdx.x;
  const int lane = t & 63;
  const int w = t >> 6;
  const int wm = w >> 1, wn = w & 1;
  const int l15 = lane & 15, g = lane >> 4;

  const unsigned short* Ab = A + (size_t)blockIdx.x * 128 * K;
  const unsigned short* Bb = Bt + (size_t)blockIdx.y * 128 * K;

  f32x4 acc[4][4] = {};

  for (int k0 = 0; k0 < K; k0 += 64) {
    __syncthreads();
#pragma unroll
    for (int i = 0; i < 4; ++i) {
      int id = i * 256 + t;
      gload_lds16(Ab + (size_t)(id >> 3) * K + k0 + (id & 7) * 8, &lA[id * 8]);
    }
#pragma unroll
    for (int i = 0; i < 4; ++i) {
      int id = i * 256 + t;
      gload_lds16(Bb + (size_t)(id >> 3) * K + k0 + (id & 7) * 8, &lB[id * 8]);
    }
    __syncthreads();
#pragma unroll
    for (int kk = 0; kk < 2; ++kk) {
      bf16x8 af[4], bfr[4];
#pragma unroll
      for (int mi = 0; mi < 4; ++mi)
        af[mi] = *(const bf16x8*)&lA[(wm * 64 + mi * 16 + l15) * 64 + kk * 32 + g * 8];
#pragma unroll
      for (int ni = 0; ni < 4; ++ni)
        bfr[ni] = *(const bf16x8*)&lB[(wn * 64 + ni * 16 + l15) * 64 + kk * 32 + g * 8];
      __builtin_amdgcn_s_setprio(1);
#pragma unroll
      for (int mi = 0; mi < 4; ++mi)
#pragma unroll
        for (int ni = 0; ni < 4; ++ni)
          acc[mi][ni] = __builtin_amdgcn_mfma_f32_16x16x32_bf16(af[mi], bfr[ni], acc[mi][ni], 0, 0, 0);
      __builtin_amdgcn_s_setprio(0);
    }
  }

#pragma unroll
  for (int mi = 0; mi < 4; ++mi)
#pragma unroll
    for (int ni = 0; ni < 4; ++ni) {
      const int col = blockIdx.y * 128 + wn * 64 + ni * 16 + l15;
      const float bcol = bias[col];
      if (z == 2) {
        const int hh = col >> 6, d = col & 63;
        const int row0 = blockIdx.x * 128 + wm * 64 + mi * 16 + g * 4;
        const int bb = row0 >> 11, nn = row0 & (N_ - 1);
        uint2 o;
        o.x = pk2(acc[mi][ni][0] + bcol, acc[mi][ni][1] + bcol);
        o.y = pk2(acc[mi][ni][2] + bcol, acc[mi][ni][3] + bcol);
        *(uint2*)(O2 + ((size_t)((bb * H_ + hh) * HD_ + d)) * N_ + nn) = o;
      } else {
        unsigned short* outB = z == 0 ? O0 : O1;
#pragma unroll
        for (int r = 0; r < 4; ++r) {
          const int row = blockIdx.x * 128 + wm * 64 + mi * 16 + g * 4 + r;
          outB[(size_t)row * Nn + col] = f2bf((acc[mi][ni][r] + bcol) * sc);
        }
      }
    }
}

// ---------------- 128x128 GEMM (single-buffer, 3 blocks/CU) with epilogues ----------------
template <int EPI>
__global__ __launch_bounds__(256, 3)
void gemm_bt(const unsigned short* __restrict__ A, const unsigned short* __restrict__ Bt,
             const float* __restrict__ bias, const float* __restrict__ resid,
             float* __restrict__ outF, unsigned short* __restrict__ outB,
             int M, int N, int K) {
  __shared__ unsigned short lA[128 * 64];
  __shared__ unsigned short lB[128 * 64];
  const int t = threadIdx.x;
  const int lane = t & 63;
  const int w = t >> 6;
  const int wm = w >> 1, wn = w & 1;
  const int l15 = lane & 15, g = lane >> 4;

  const unsigned short* Ab = A + (size_t)blockIdx.x * 128 * K;
  const unsigned short* Bb = Bt + (size_t)blockIdx.y * 128 * K;

  f32x4 acc[4][4] = {};

  for (int k0 = 0; k0 < K; k0 += 64) {
    __syncthreads();
#pragma unroll
    for (int i = 0; i < 4; ++i) {
      int id = i * 256 + t;
      gload_lds16(Ab + (size_t)(id >> 3) * K + k0 + (id & 7) * 8, &lA[id * 8]);
    }
#pragma unroll
    for (int i = 0; i < 4; ++i) {
      int id = i * 256 + t;
      gload_lds16(Bb + (size_t)(id >> 3) * K + k0 + (id & 7) * 8, &lB[id * 8]);
    }
    __syncthreads();
#pragma unroll
    for (int kk = 0; kk < 2; ++kk) {
      bf16x8 af[4], bfr[4];
#pragma unroll
      for (int mi = 0; mi < 4; ++mi)
        af[mi] = *(const bf16x8*)&lA[(wm * 64 + mi * 16 + l15) * 64 + kk * 32 + g * 8];
#pragma unroll
      for (int ni = 0; ni < 4; ++ni)
        bfr[ni] = *(const bf16x8*)&lB[(wn * 64 + ni * 16 + l15) * 64 + kk * 32 + g * 8];
      __builtin_amdgcn_s_setprio(1);
#pragma unroll
      for (int mi = 0; mi < 4; ++mi)
#pragma unroll
        for (int ni = 0; ni < 4; ++ni)
          acc[mi][ni] = __builtin_amdgcn_mfma_f32_16x16x32_bf16(af[mi], bfr[ni], acc[mi][ni], 0, 0, 0);
      __builtin_amdgcn_s_setprio(0);
    }
  }

#pragma unroll
  for (int mi = 0; mi < 4; ++mi)
#pragma unroll
    for (int ni = 0; ni < 4; ++ni) {
      const int col = blockIdx.y * 128 + wn * 64 + ni * 16 + l15;
      const float bcol = bias[col];
#pragma unroll
      for (int r = 0; r < 4; ++r) {
        const int row = blockIdx.x * 128 + wm * 64 + mi * 16 + g * 4 + r;
        const size_t o = (size_t)row * N + col;
        float val = acc[mi][ni][r] + bcol;
        if (EPI == 0) {
          outB[o] = f2bf(val);
        } else if (EPI == 1) {
          outF[o] = val + resid[o];
        } else {
          float ge = 0.5f * val * (1.0f + erff(val * 0.70710678118654752f));
          outB[o] = f2bf(ge);
        }
      }
    }
}

// ---------------- 128x64-tile GEMM (single-buffer, 4 blocks/CU; skinny N) ----------------
// MODE 0: resid f32 (q), out bf16 = val + bias + resid   (o-proj -> xfb)
// MODE 1: resid bf16 (xfb), out f32 = val + bias + resid (ffn-down -> d_out)
template <int MODE>
__global__ __launch_bounds__(256, 4)
void gemm_n64(const unsigned short* __restrict__ A, const unsigned short* __restrict__ Bt,
              const float* __restrict__ bias, const void* __restrict__ residv,
              float* __restrict__ outF, unsigned short* __restrict__ outB,
              int M, int N, int K) {
  __shared__ unsigned short lA[128 * 64];
  __shared__ unsigned short lB[64 * 64];
  const int t = threadIdx.x;
  const int lane = t & 63;
  const int w = t >> 6;
  const int wm = w >> 1, wn = w & 1;
  const int l15 = lane & 15, g = lane >> 4;

  const unsigned short* Ab = A + (size_t)blockIdx.x * 128 * K;
  const unsigned short* Bb = Bt + (size_t)blockIdx.y * 64 * K;

  f32x4 acc[4][2] = {};

  for (int k0 = 0; k0 < K; k0 += 64) {
    __syncthreads();
#pragma unroll
    for (int i = 0; i < 4; ++i) {
      int id = i * 256 + t;
      gload_lds16(Ab + (size_t)(id >> 3) * K + k0 + (id & 7) * 8, &lA[id * 8]);
    }
#pragma unroll
    for (int i = 0; i < 2; ++i) {
      int id = i * 256 + t;
      gload_lds16(Bb + (size_t)(id >> 3) * K + k0 + (id & 7) * 8, &lB[id * 8]);
    }
    __syncthreads();
#pragma unroll
    for (int kk = 0; kk < 2; ++kk) {
      bf16x8 af[4], bfr[2];
#pragma unroll
      for (int mi = 0; mi < 4; ++mi)
        af[mi] = *(const bf16x8*)&lA[(wm * 64 + mi * 16 + l15) * 64 + kk * 32 + g * 8];
#pragma unroll
      for (int ni = 0; ni < 2; ++ni)
        bfr[ni] = *(const bf16x8*)&lB[(wn * 32 + ni * 16 + l15) * 64 + kk * 32 + g * 8];
      __builtin_amdgcn_s_setprio(1);
#pragma unroll
      for (int mi = 0; mi < 4; ++mi)
#pragma unroll
        for (int ni = 0; ni < 2; ++ni)
          acc[mi][ni] = __builtin_amdgcn_mfma_f32_16x16x32_bf16(af[mi], bfr[ni], acc[mi][ni], 0, 0, 0);
      __builtin_amdgcn_s_setprio(0);
    }
  }

#pragma unroll
  for (int mi = 0; mi < 4; ++mi)
#pragma unroll
    for (int ni = 0; ni < 2; ++ni) {
      const int col = blockIdx.y * 64 + wn * 32 + ni * 16 + l15;
      const float bcol = bias[col];
#pragma unroll
      for (int r = 0; r < 4; ++r) {
        const int row = blockIdx.x * 128 + wm * 64 + mi * 16 + g * 4 + r;
        const size_t o = (size_t)row * N + col;
        const float val = acc[mi][ni][r] + bcol;
        if (MODE == 0) {
          const float* resid = (const float*)residv;
          outB[o] = f2bf(val + resid[o]);
        } else {
          const unsigned short* resid = (const unsigned short*)residv;
          outF[o] = val + bf2f(resid[o]);
        }
      }
    }
}

// ---------------- flash attention (r13-best: 32x32 MFMA + permlane32_swap) ----------------
__global__ __launch_bounds__(256, 2)
void attn_fwd(const unsigned short* __restrict__ Qh, const unsigned short* __restrict__ Kh,
              const unsigned short* __restrict__ VhT, unsigned short* __restrict__ ctx) {
  __shared__ unsigned short lK[2][64 * 64];
  __shared__ unsigned short lV[2][64 * 64];

  const int t = threadIdx.x, lane = t & 63, w = t >> 6;
  const int l31 = lane & 31, hl = lane >> 5;
  const int swz = xcd_chunk(blockIdx.x, (N_ / 128) * B_ * H_);
  const int bx = swz & (N_ / 128 - 1), bh = swz >> 4;
  const int b = bh >> 4, h = bh & 15;
  const int qb0 = bx * 128 + w * 32;

  const unsigned short* Qb = Qh + (size_t)b * N_ * C_ + h * HD_;
  const unsigned short* Kb = Kh + (size_t)b * N_ * C_ + h * HD_;
  const unsigned short* Vb = VhT + (size_t)bh * HD_ * N_;

  bf16x8 qf[4];
#pragma unroll
  for (int f = 0; f < 4; ++f)
    qf[f] = *(const bf16x8*)(Qb + (size_t)(qb0 + l31) * C_ + f * 16 + hl * 8);

  auto stageK = [&](int buf, int kb) {
#pragma unroll
    for (int i = 0; i < 2; ++i) {
      int o = (i * 256 + t) * 16;
      int r = o >> 7;
      int c = (o & 127) ^ ((r & 7) << 4);
      gload_lds16(Kb + (size_t)(kb + r) * C_ + (c >> 1), &lK[buf][o >> 1]);
    }
  };
  auto stageV = [&](int buf, int kb) {
#pragma unroll
    for (int i = 0; i < 2; ++i) {
      int o = (i * 256 + t) * 16;
      int r = o >> 7;
      int c = (o & 127) ^ ((r & 7) << 4);
      gload_lds16(Vb + (size_t)r * N_ + kb + (c >> 1), &lV[buf][o >> 1]);
    }
  };

  f32x16 od[2] = {};
  float mrun = -1e30f;
  float srun = 0.f;
  const float DTHR = 11.541560327111707f;  // 8 * log2(e)
  const int NT = N_ / 64;
  const int sw = (l31 & 7) << 4;

  stageK(0, 0);
  stageV(0, 0);

  int cur = 0;
  for (int tile = 0; tile < NT; ++tile) {
    if (tile + 1 < NT) {
      stageK(cur ^ 1, (tile + 1) * 64);
      stageV(cur ^ 1, (tile + 1) * 64);
      WAITVM(4);
    } else {
      WAITVM(0);
    }
    __builtin_amdgcn_s_barrier();

    f32x16 st[2];
    __builtin_amdgcn_s_setprio(1);
#pragma unroll
    for (int kb2 = 0; kb2 < 2; ++kb2) {
      f32x16 z = {};
#pragma unroll
      for (int f = 0; f < 4; ++f) {
        const int byt = (kb2 * 32 + l31) * 128 + ((f * 32 + hl * 16) ^ sw);
        const bf16x8 ka = *(const bf16x8*)&lK[cur][byt >> 1];
        z = __builtin_amdgcn_mfma_f32_32x32x16_bf16(ka, qf[f], z, 0, 0, 0);
      }
      st[kb2] = z;
    }
    __builtin_amdgcn_s_setprio(0);

    float mx = st[0][0];
#pragma unroll
    for (int r = 1; r < 16; ++r) mx = fmaxf(mx, st[0][r]);
#pragma unroll
    for (int r = 0; r < 16; ++r) mx = fmaxf(mx, st[1][r]);
    mx = fmaxf(mx, __shfl_xor(mx, 32));
    if (__any(mx > mrun + DTHR)) {
      const float mn = fmaxf(mrun, mx);
      const float sf = exp2f(mrun - mn);
      mrun = mn;
      srun *= sf;
#pragma unroll
      for (int dblk = 0; dblk < 2; ++dblk)
#pragma unroll
        for (int r = 0; r < 16; ++r) od[dblk][r] *= sf;
    }

    bf16x8 pb[4];
#pragma unroll
    for (int kb2 = 0; kb2 < 2; ++kb2) {
      float p[16];
#pragma unroll
      for (int r = 0; r < 16; ++r) {
        p[r] = exp2f(st[kb2][r] - mrun);
        srun += p[r];
      }
      unsigned qd[8];
#pragma unroll
      for (int i = 0; i < 8; ++i) qd[i] = pk2(p[2 * i], p[2 * i + 1]);
      pl32swap(qd[0], qd[2]);
      pl32swap(qd[1], qd[3]);
      pl32swap(qd[4], qd[6]);
      pl32swap(qd[5], qd[7]);
      union { unsigned u[4]; bf16x8 v; } f0, f1;
      f0.u[0] = qd[0];
      f0.u[1] = qd[1];
      f0.u[2] = qd[2];
      f0.u[3] = qd[3];
      f1.u[0] = qd[4];
      f1.u[1] = qd[5];
      f1.u[2] = qd[6];
      f1.u[3] = qd[7];
      pb[kb2 * 2 + 0] = f0.v;
      pb[kb2 * 2 + 1] = f1.v;
    }

    __builtin_amdgcn_s_setprio(1);
#pragma unroll
    for (int dblk = 0; dblk < 2; ++dblk) {
#pragma unroll
      for (int kf = 0; kf < 4; ++kf) {
        const int byt = (dblk * 32 + l31) * 128 + ((kf * 32 + hl * 16) ^ sw);
        const bf16x8 va = *(const bf16x8*)&lV[cur][byt >> 1];
        od[dblk] = __builtin_amdgcn_mfma_f32_32x32x16_bf16(va, pb[kf], od[dblk], 0, 0, 0);
      }
    }
    __builtin_amdgcn_s_setprio(0);

    WAITLGKM0;
    __builtin_amdgcn_s_barrier();
    cur ^= 1;
  }

  float s = srun + __shfl_xor(srun, 32);
  const float rinv = 1.0f / s;
  unsigned short* cp = ctx + ((size_t)(b * N_ + qb0 + l31)) * C_ + h * HD_;
#pragma unroll
  for (int dblk = 0; dblk < 2; ++dblk)
#pragma unroll
    for (int a = 0; a < 4; ++a) {
      const int r0 = a * 4;
      uint2 o;
      o.x = pk2(od[dblk][r0] * rinv, od[dblk][r0 + 1] * rinv);
      o.y = pk2(od[dblk][r0 + 2] * rinv, od[dblk][r0 + 3] * rinv);
      *(uint2*)(cp + dblk * 32 + a * 8 + hl * 4) = o;
    }
}

// ---------------- LayerNorm: x bf16 [BN, C] -> h bf16, wave-per-row ----------------
__global__ __launch_bounds__(256)
void ln_kernel(const unsigned short* __restrict__ x, const float* __restrict__ lw,
               const float* __restrict__ lb, unsigned short* __restrict__ h) {
  const int w = threadIdx.x >> 6, lane = threadIdx.x & 63;
  const int row = blockIdx.x * 4 + w;
  const uint4* xr = (const uint4*)(x + (size_t)row * C_);
  uint4 rv[2];
  float xv[16];
  float sum = 0.f;
#pragma unroll
  for (int i = 0; i < 2; ++i) {
    rv[i] = xr[lane + i * 64];
    const unsigned uu[4] = {rv[i].x, rv[i].y, rv[i].z, rv[i].w};
#pragma unroll
    for (int j = 0; j < 4; ++j) {
      xv[i * 8 + 2 * j]     = bf2f((unsigned short)(uu[j] & 0xffffu));
      xv[i * 8 + 2 * j + 1] = bf2f((unsigned short)(uu[j] >> 16));
      sum += xv[i * 8 + 2 * j] + xv[i * 8 + 2 * j + 1];
    }
  }
#pragma unroll
  for (int m = 1; m < 64; m <<= 1) sum += __shfl_xor(sum, m);
  const float mu = sum * (1.0f / C_);
  float sq = 0.f;
#pragma unroll
  for (int e = 0; e < 16; ++e) {
    const float d = xv[e] - mu;
    sq += d * d;
  }
#pragma unroll
  for (int m = 1; m < 64; m <<= 1) sq += __shfl_xor(sq, m);
  const float rstd = rsqrtf(sq * (1.0f / C_) + 1e-5f);
  uint4* ho = (uint4*)(h + (size_t)row * C_);
#pragma unroll
  for (int i = 0; i < 2; ++i) {
    const int e0 = (lane + i * 64) * 8;
    uint4 o;
    unsigned* op = (unsigned*)&o;
#pragma unroll
    for (int j = 0; j < 4; ++j) {
      const float a = (xv[i * 8 + 2 * j] - mu) * rstd * lw[e0 + 2 * j] + lb[e0 + 2 * j];
      const float bvl = (xv[i * 8 + 2 * j + 1] - mu) * rstd * lw[e0 + 2 * j + 1] + lb[e0 + 2 * j + 1];
      op[j] = pk2(a, bvl);
    }
    ho[lane + i * 64] = o;
  }
}

extern "C" void kernel_launch(void* const* d_in, const int* in_sizes, int n_in,
                              void* d_out, int out_size, void* d_ws, size_t ws_size,
                              hipStream_t stream) {
  const float* q   = (const float*)d_in[0];
  const float* k   = (const float*)d_in[1];
  const float* v   = (const float*)d_in[2];
  const float* Wq  = (const float*)d_in[3];
  const float* bq  = (const float*)d_in[4];
  const float* Wk  = (const float*)d_in[5];
  const float* bk  = (const float*)d_in[6];
  const float* Wv  = (const float*)d_in[7];
  const float* bv  = (const float*)d_in[8];
  const float* Wo  = (const float*)d_in[9];
  const float* bo  = (const float*)d_in[10];
  const float* lnw = (const float*)d_in[11];
  const float* lnb = (const float*)d_in[12];
  const float* W1  = (const float*)d_in[13];
  const float* b1  = (const float*)d_in[14];
  const float* W2  = (const float*)d_in[15];
  const float* b2  = (const float*)d_in[16];
  float* out = (float*)d_out;

  char* ws = (char*)d_ws;
  const size_t MB = 1024 * 1024;
  if (ws_size < 120 * MB) return;
  unsigned short* qb   = (unsigned short*)(ws + 0 * MB);
  unsigned short* kb   = (unsigned short*)(ws + 8 * MB);
  unsigned short* vb   = (unsigned short*)(ws + 16 * MB);
  unsigned short* Wqt  = (unsigned short*)(ws + 24 * MB);
  unsigned short* Wkt  = (unsigned short*)(ws + 26 * MB);
  unsigned short* Wvt  = (unsigned short*)(ws + 28 * MB);
  unsigned short* Wot  = (unsigned short*)(ws + 30 * MB);
  unsigned short* W1t  = (unsigned short*)(ws + 32 * MB);
  unsigned short* W2t  = (unsigned short*)(ws + 36 * MB);
  unsigned short* Qh   = (unsigned short*)(ws + 40 * MB);
  unsigned short* Kh   = (unsigned short*)(ws + 48 * MB);
  unsigned short* VhT  = (unsigned short*)(ws + 64 * MB);
  unsigned short* ctx  = (unsigned short*)(ws + 72 * MB);
  unsigned short* xfb  = (unsigned short*)(ws + 80 * MB);  // bf16 residual x (8 MB)
  unsigned short* hb   = (unsigned short*)(ws + 96 * MB);
  unsigned short* tbuf = (unsigned short*)(ws + 104 * MB);

  prep<<<dim3(14336), 256, 0, stream>>>(q, k, v, Wq, Wk, Wv, Wo, W1, W2,
                                        qb, kb, vb, Wqt, Wkt, Wvt, Wot, W1t, W2t);

  gemm_qkv<<<dim3(B_ * N_ / 128, C_ / 128, 3), 256, 0, stream>>>(qb, kb, vb, Wqt, Wkt, Wvt,
                                                                 bq, bk, bv, Qh, Kh, VhT);

  attn_fwd<<<dim3((N_ / 128) * B_ * H_), 256, 0, stream>>>(Qh, Kh, VhT, ctx);

  gemm_n64<0><<<dim3(B_ * N_ / 128, C_ / 64), 256, 0, stream>>>(ctx, Wot, bo, q, nullptr, xfb,
                                                                B_ * N_, C_, C_);
  ln_kernel<<<dim3(B_ * N_ / 4), 256, 0, stream>>>(xfb, lnw, lnb, hb);
  gemm_bt<2><<<dim3(B_ * N_ / 128, FF_ / 128), 256, 0, stream>>>(hb, W1t, b1, nullptr, nullptr, tbuf,
                                                                 B_ * N_, FF_, C_);
  gemm_n64<1><<<dim3(B_ * N_ / 128, C_ / 64), 256, 0, stream>>>(tbuf, W2t, b2, xfb, out, nullptr,
                                                                B_ * N_, C_, FF_);
}